// Round 1
// baseline (2578.490 us; speedup 1.0000x reference)
//
#include <hip/hip_runtime.h>

// ---------------- problem constants ----------------
constexpr int D   = 1024;
constexpr int H   = 16;
constexpr int FFN = 4096;
constexpr int SEG = 128;
constexpr int L   = 32;
constexpr int RCL = 4;
constexpr int T   = 2048;
constexpr int B   = 2;
constexpr int N   = T / SEG;   // 16
constexpr int M   = N - 1;     // 15
constexpr int R   = RCL * N;   // 64
constexpr int S   = N;         // 16
constexpr int Q   = R + T + S; // 2128
constexpr int KV  = M + R + T; // 2127
constexpr int RT  = R + T;     // 2112
constexpr float EPS = 1e-5f;

// ---------------- small helpers ----------------
__device__ inline void block_reduce_2(float& s1, float& s2) {
    #pragma unroll
    for (int off = 32; off > 0; off >>= 1) {
        s1 += __shfl_xor(s1, off, 64);
        s2 += __shfl_xor(s2, off, 64);
    }
    __shared__ float red[8];
    int lane = threadIdx.x & 63, w = threadIdx.x >> 6;
    if (lane == 0) { red[w * 2] = s1; red[w * 2 + 1] = s2; }
    __syncthreads();
    s1 = red[0] + red[2] + red[4] + red[6];
    s2 = red[1] + red[3] + red[5] + red[7];
}

// ---------------- float4 copy ----------------
__global__ __launch_bounds__(256) void copy4_kernel(const float* __restrict__ src,
                                                    float* __restrict__ dst, int n4) {
    int idx = blockIdx.x * 256 + threadIdx.x;
    if (idx < n4) {
        reinterpret_cast<float4*>(dst)[idx] = reinterpret_cast<const float4*>(src)[idx];
    }
}

// ---------------- LayerNorm (one block per row, D=1024) ----------------
// src row = row < split ? src0[row] : src1[row-split]
// dst0 always written (remap==1 applies the final-output row remap); dst1 optional.
__global__ __launch_bounds__(256) void ln_kernel(const float* __restrict__ src0,
                                                 const float* __restrict__ src1,
                                                 int split,
                                                 float* __restrict__ dst0,
                                                 float* __restrict__ dst1,
                                                 const float* __restrict__ gamma,
                                                 const float* __restrict__ beta,
                                                 int remap) {
    int row = blockIdx.x;
    int t = threadIdx.x;
    const float* src = (row < split) ? src0 + (size_t)row * D
                                     : src1 + (size_t)(row - split) * D;
    float4 x = *reinterpret_cast<const float4*>(&src[t * 4]);
    float s1 = x.x + x.y + x.z + x.w;
    float s2 = x.x * x.x + x.y * x.y + x.z * x.z + x.w * x.w;
    block_reduce_2(s1, s2);
    float mean = s1 * (1.0f / D);
    float var  = s2 * (1.0f / D) - mean * mean;
    float rs = rsqrtf(var + EPS);
    float4 g4 = *reinterpret_cast<const float4*>(&gamma[t * 4]);
    float4 b4 = *reinterpret_cast<const float4*>(&beta[t * 4]);
    float4 y;
    y.x = (x.x - mean) * rs * g4.x + b4.x;
    y.y = (x.y - mean) * rs * g4.y + b4.y;
    y.z = (x.z - mean) * rs * g4.z + b4.z;
    y.w = (x.w - mean) * rs * g4.w + b4.w;
    size_t off;
    if (!remap) {
        off = (size_t)row * D;
    } else {
        // final output: rows [0,R*B) -> region B at T*B*D; rows [R*B,..) -> region A at 0
        off = (row < R * B) ? ((size_t)T * B * D + (size_t)row * D)
                            : ((size_t)(row - R * B) * D);
    }
    *reinterpret_cast<float4*>(&dst0[off + t * 4]) = y;
    if (dst1) *reinterpret_cast<float4*>(&dst1[(size_t)row * D + t * 4]) = y;
}

// ---------------- summary (mean over SEG rows) ----------------
// qx holds ln rows [0, RT*B); writes summary into qx rows [RT*B, Q*B)
__global__ __launch_bounds__(256) void summary_kernel(float* __restrict__ qx) {
    int nb = blockIdx.x;          // N*B = 32
    int n = nb >> 1, b = nb & 1;
    int t = threadIdx.x;
    float4 acc = make_float4(0.f, 0.f, 0.f, 0.f);
    for (int s = 0; s < SEG; ++s) {
        size_t base = ((size_t)((R + n * SEG + s) * B + b)) * D + t * 4;
        float4 x = *reinterpret_cast<const float4*>(&qx[base]);
        acc.x += x.x; acc.y += x.y; acc.z += x.z; acc.w += x.w;
    }
    const float inv = 1.0f / SEG;
    acc.x *= inv; acc.y *= inv; acc.z *= inv; acc.w *= inv;
    size_t dst = ((size_t)(RT + n) * B + b) * D + t * 4;
    *reinterpret_cast<float4*>(&qx[dst]) = acc;
}

// ---------------- fp32 GEMM:  C[m][n] = (sum_k A[m][k]*W[n][k] + bias[n]) * alpha
//                  optional relu, optional residual add (ld = ldc) ----------------
constexpr int BM = 128, BN = 128, BK = 16;

__global__ __launch_bounds__(256) void sgemm_nt(const float* __restrict__ A, int lda,
                                                const float* __restrict__ W, int ldw,
                                                const float* __restrict__ bias,
                                                const float* __restrict__ residual,
                                                float* __restrict__ C, int ldc,
                                                int Mr, int Nc, int Kd,
                                                float alpha, int do_relu) {
    __shared__ __align__(16) float As[BK][BM + 4];
    __shared__ __align__(16) float Bs[BK][BN + 4];
    int t = threadIdx.x;
    int tx = t & 15, ty = t >> 4;
    int bm0 = blockIdx.y * BM;
    int bn0 = blockIdx.x * BN;

    float acc[8][8];
    #pragma unroll
    for (int i = 0; i < 8; ++i)
        #pragma unroll
        for (int j = 0; j < 8; ++j) acc[i][j] = 0.f;

    for (int k0 = 0; k0 < Kd; k0 += BK) {
        #pragma unroll
        for (int l = 0; l < 2; ++l) {
            int f = t + l * 256;
            int row = f >> 2, kc = f & 3;
            int grow = bm0 + row;
            float4 v = make_float4(0.f, 0.f, 0.f, 0.f);
            if (grow < Mr) v = *reinterpret_cast<const float4*>(&A[(size_t)grow * lda + k0 + kc * 4]);
            As[kc * 4 + 0][row] = v.x;
            As[kc * 4 + 1][row] = v.y;
            As[kc * 4 + 2][row] = v.z;
            As[kc * 4 + 3][row] = v.w;
            int wrow = bn0 + row;
            float4 u = make_float4(0.f, 0.f, 0.f, 0.f);
            if (wrow < Nc) u = *reinterpret_cast<const float4*>(&W[(size_t)wrow * ldw + k0 + kc * 4]);
            Bs[kc * 4 + 0][row] = u.x;
            Bs[kc * 4 + 1][row] = u.y;
            Bs[kc * 4 + 2][row] = u.z;
            Bs[kc * 4 + 3][row] = u.w;
        }
        __syncthreads();
        #pragma unroll
        for (int kk = 0; kk < BK; ++kk) {
            float4 a0 = *reinterpret_cast<const float4*>(&As[kk][ty * 4]);
            float4 a1 = *reinterpret_cast<const float4*>(&As[kk][64 + ty * 4]);
            float4 b0 = *reinterpret_cast<const float4*>(&Bs[kk][tx * 4]);
            float4 b1 = *reinterpret_cast<const float4*>(&Bs[kk][64 + tx * 4]);
            float ar[8] = {a0.x, a0.y, a0.z, a0.w, a1.x, a1.y, a1.z, a1.w};
            float br[8] = {b0.x, b0.y, b0.z, b0.w, b1.x, b1.y, b1.z, b1.w};
            #pragma unroll
            for (int rr = 0; rr < 8; ++rr)
                #pragma unroll
                for (int cc = 0; cc < 8; ++cc)
                    acc[rr][cc] += ar[rr] * br[cc];
        }
        __syncthreads();
    }

    #pragma unroll
    for (int rh = 0; rh < 2; ++rh) {
        #pragma unroll
        for (int rr = 0; rr < 4; ++rr) {
            int grow = bm0 + rh * 64 + ty * 4 + rr;
            if (grow >= Mr) continue;
            #pragma unroll
            for (int ch = 0; ch < 2; ++ch) {
                int gcol = bn0 + ch * 64 + tx * 4;
                float4 bv = *reinterpret_cast<const float4*>(&bias[gcol]);
                float4 o;
                o.x = (acc[rh * 4 + rr][ch * 4 + 0] + bv.x) * alpha;
                o.y = (acc[rh * 4 + rr][ch * 4 + 1] + bv.y) * alpha;
                o.z = (acc[rh * 4 + rr][ch * 4 + 2] + bv.z) * alpha;
                o.w = (acc[rh * 4 + rr][ch * 4 + 3] + bv.w) * alpha;
                if (do_relu) {
                    o.x = fmaxf(o.x, 0.f); o.y = fmaxf(o.y, 0.f);
                    o.z = fmaxf(o.z, 0.f); o.w = fmaxf(o.w, 0.f);
                }
                if (residual) {
                    float4 rv = *reinterpret_cast<const float4*>(&residual[(size_t)grow * ldc + gcol]);
                    o.x += rv.x; o.y += rv.y; o.z += rv.z; o.w += rv.w;
                }
                *reinterpret_cast<float4*>(&C[(size_t)grow * ldc + gcol]) = o;
            }
        }
    }
}

// ---------------- sparse masked attention ----------------
// One block per (segment group i, batch b, head h). Allowed cols per group:
//   mems [0,i) ; rc [M+i*RCL, M+(i+1)*RCL) ; utt [M+R+max(0,i*SEG-L), M+R+(i+1)*SEG)
// Masked cols are exactly exp(-1e8 - m) == 0 in fp32 -> sparse softmax is exact.
constexpr int CMAX = 192;   // max allowed cols = 179
constexpr int KTS  = 193;   // Kt LDS row stride (odd -> conflict-free)

__global__ __launch_bounds__(256) void attn_sparse(const float* __restrict__ qb,
                                                   const float* __restrict__ kb,
                                                   const float* __restrict__ vb,
                                                   const int* __restrict__ lengths,
                                                   float* __restrict__ attn) {
    __shared__ __align__(16) float Kt[64 * KTS];       // [d][c] transposed
    __shared__ __align__(16) float Vt[CMAX * 64];      // [c][d]
    __shared__ __align__(16) float qs[4][64];
    __shared__ __align__(16) float ps[4][192];
    __shared__ int colmap[CMAX];

    int gid = blockIdx.x;
    int i  = gid & 15;
    int bh = gid >> 4;
    int b  = bh >> 4;
    int h  = bh & 15;
    int t = threadIdx.x;
    int lane = t & 63, w = t >> 6;

    int nm = i;
    int u0 = (i * SEG - L > 0) ? (i * SEG - L) : 0;
    int nu = (i + 1) * SEG - u0;
    int nc = nm + RCL + nu;

    int maxlen = max(lengths[0], lengths[1]);
    int kl = lengths[b] + (M + R + T) - maxlen;

    for (int c = t; c < nc; c += 256) {
        int g;
        if (c < nm)            g = c;
        else if (c < nm + RCL) g = M + i * RCL + (c - nm);
        else                   g = M + R + u0 + (c - nm - RCL);
        colmap[c] = g;
    }
    __syncthreads();

    for (int f = t; f < nc * 16; f += 256) {
        int c = f >> 4, dc = f & 15;
        int g = colmap[c];
        size_t base = ((size_t)g * B + b) * D + h * 64 + dc * 4;
        float4 k4 = *reinterpret_cast<const float4*>(&kb[base]);
        Kt[(dc * 4 + 0) * KTS + c] = k4.x;
        Kt[(dc * 4 + 1) * KTS + c] = k4.y;
        Kt[(dc * 4 + 2) * KTS + c] = k4.z;
        Kt[(dc * 4 + 3) * KTS + c] = k4.w;
        float4 v4 = *reinterpret_cast<const float4*>(&vb[base]);
        *reinterpret_cast<float4*>(&Vt[c * 64 + dc * 4]) = v4;
    }
    __syncthreads();

    const int nrow = RCL + SEG + 1;   // 133 query rows per group
    for (int r = w; r < nrow; r += 4) {
        int qrow;
        if (r < RCL)            qrow = i * RCL + r;
        else if (r < RCL + SEG) qrow = R + i * SEG + (r - RCL);
        else                    qrow = R + T + i;

        qs[w][lane] = qb[((size_t)qrow * B + b) * D + h * 64 + lane];
        // same-wave LDS ops are in-order; no block barrier needed for qs/ps

        int c0 = lane, c1 = lane + 64, c2 = lane + 128;
        float a0 = 0.f, a1 = 0.f, a2 = 0.f;
        #pragma unroll
        for (int d = 0; d < 64; d += 4) {
            float4 qv = *reinterpret_cast<const float4*>(&qs[w][d]);
            a0 += qv.x * Kt[(d + 0) * KTS + c0] + qv.y * Kt[(d + 1) * KTS + c0]
                + qv.z * Kt[(d + 2) * KTS + c0] + qv.w * Kt[(d + 3) * KTS + c0];
            a1 += qv.x * Kt[(d + 0) * KTS + c1] + qv.y * Kt[(d + 1) * KTS + c1]
                + qv.z * Kt[(d + 2) * KTS + c1] + qv.w * Kt[(d + 3) * KTS + c1];
            a2 += qv.x * Kt[(d + 0) * KTS + c2] + qv.y * Kt[(d + 1) * KTS + c2]
                + qv.z * Kt[(d + 2) * KTS + c2] + qv.w * Kt[(d + 3) * KTS + c2];
        }
        bool v0 = (c0 < nc) && (colmap[c0] < kl);
        bool v1 = (c1 < nc) && (colmap[c1] < kl);
        bool v2 = (c2 < nc) && (colmap[c2] < kl);
        float s0 = v0 ? a0 : -1e30f;
        float s1 = v1 ? a1 : -1e30f;
        float s2 = v2 ? a2 : -1e30f;

        float m = fmaxf(fmaxf(s0, s1), s2);
        #pragma unroll
        for (int off = 32; off > 0; off >>= 1) m = fmaxf(m, __shfl_xor(m, off, 64));

        float p0 = __expf(s0 - m), p1 = __expf(s1 - m), p2 = __expf(s2 - m);
        float sum = p0 + p1 + p2;
        #pragma unroll
        for (int off = 32; off > 0; off >>= 1) sum += __shfl_xor(sum, off, 64);

        ps[w][c0] = p0; ps[w][c1] = p1; ps[w][c2] = p2;

        float o = 0.f;
        int c = 0;
        for (; c + 4 <= nc; c += 4) {
            o += ps[w][c + 0] * Vt[(c + 0) * 64 + lane]
               + ps[w][c + 1] * Vt[(c + 1) * 64 + lane]
               + ps[w][c + 2] * Vt[(c + 2) * 64 + lane]
               + ps[w][c + 3] * Vt[(c + 3) * 64 + lane];
        }
        for (; c < nc; ++c) o += ps[w][c] * Vt[c * 64 + lane];

        attn[((size_t)qrow * B + b) * D + h * 64 + lane] = o / sum;
    }
}

// ---------------- residual add + mems clip ----------------
__global__ __launch_bounds__(256) void resid_clip(const float* __restrict__ obuf,
                                                  const float* __restrict__ rc,
                                                  const float* __restrict__ utt,
                                                  float* __restrict__ result,
                                                  float* __restrict__ out_mems) {
    size_t idx = (size_t)blockIdx.x * 256 + threadIdx.x;
    size_t f = idx * 4;
    if (f >= (size_t)Q * B * D) return;
    int row = (int)(f >> 10);  // D = 1024
    float4 o = *reinterpret_cast<const float4*>(&obuf[f]);
    if (row < RT * B) {
        const float* res = (row < R * B) ? &rc[f] : &utt[f - (size_t)R * B * D];
        float4 rv = *reinterpret_cast<const float4*>(res);
        o.x += rv.x; o.y += rv.y; o.z += rv.z; o.w += rv.w;
        *reinterpret_cast<float4*>(&result[f]) = o;
    } else {
        o.x = fminf(fmaxf(o.x, -10.f), 10.f);
        o.y = fminf(fmaxf(o.y, -10.f), 10.f);
        o.z = fminf(fmaxf(o.z, -10.f), 10.f);
        o.w = fminf(fmaxf(o.w, -10.f), 10.f);
        *reinterpret_cast<float4*>(&out_mems[f - (size_t)RT * B * D]) = o;
    }
}

// ---------------- launch ----------------
extern "C" void kernel_launch(void* const* d_in, const int* in_sizes, int n_in,
                              void* d_out, int out_size, void* d_ws, size_t ws_size,
                              hipStream_t stream) {
    const float* utt   = (const float*)d_in[0];
    const float* rc    = (const float*)d_in[1];
    const float* mems  = (const float*)d_in[2];
    const float* lng   = (const float*)d_in[3];
    const float* lnb   = (const float*)d_in[4];
    const float* Wq    = (const float*)d_in[5];
    const float* bq    = (const float*)d_in[6];
    const float* Wkv   = (const float*)d_in[7];
    const float* bkv   = (const float*)d_in[8];
    const float* Wo    = (const float*)d_in[9];
    const float* bo    = (const float*)d_in[10];
    const float* ffg   = (const float*)d_in[11];
    const float* ffb   = (const float*)d_in[12];
    const float* W1    = (const float*)d_in[13];
    const float* b1    = (const float*)d_in[14];
    const float* W2    = (const float*)d_in[15];
    const float* b2    = (const float*)d_in[16];
    const float* outg  = (const float*)d_in[17];
    const float* outb  = (const float*)d_in[18];
    const int*   lens  = (const int*)d_in[19];
    // d_in[20] = attention_mask (unused; structure derived analytically)

    float* ws = (float*)d_ws;
    size_t off = 0;
    auto alloc = [&](size_t n) { float* p = ws + off; off += (n + 63) & ~(size_t)63; return p; };
    float* qx   = alloc((size_t)Q * B * D);        // query-input rows (ln + summary)
    float* kvx  = alloc((size_t)KV * B * D);       // kv-input rows (mems + ln)
    float* qbuf = alloc((size_t)Q * B * D);
    float* kbuf = alloc((size_t)KV * B * D);
    float* vbuf = alloc((size_t)KV * B * D);
    float* ffh  = alloc((size_t)RT * B * FFN);
    // aliases (lifetimes verified non-overlapping):
    float* attnb  = qx;
    float* obuf   = qbuf;
    float* result = kbuf;
    float* ffln   = vbuf;
    float* res2   = kvx;
    float* out = (float*)d_out;

    // 1. mems -> kvx[0:M*B)
    copy4_kernel<<<(M * B * D / 4 + 255) / 256, 256, 0, stream>>>(mems, kvx, M * B * D / 4);
    // 2. input LN -> qx rows [0,RT*B) and kvx rows [M*B, KV*B)
    ln_kernel<<<RT * B, 256, 0, stream>>>(rc, utt, R * B, qx, kvx + (size_t)M * B * D,
                                          lng, lnb, 0);
    // 3. summary rows -> qx rows [RT*B, Q*B)
    summary_kernel<<<N * B, 256, 0, stream>>>(qx);
    // 4. q projection (scaled)
    {
        dim3 g(D / BN, (Q * B + BM - 1) / BM);
        sgemm_nt<<<g, 256, 0, stream>>>(qx, D, Wq, D, bq, nullptr, qbuf, D,
                                        Q * B, D, D, 0.125f, 0);
    }
    // 5/6. k and v projections
    {
        dim3 g(D / BN, (KV * B + BM - 1) / BM);
        sgemm_nt<<<g, 256, 0, stream>>>(kvx, D, Wkv, D, bkv, nullptr, kbuf, D,
                                        KV * B, D, D, 1.0f, 0);
        sgemm_nt<<<g, 256, 0, stream>>>(kvx, D, Wkv + (size_t)D * D, D, bkv + D, nullptr,
                                        vbuf, D, KV * B, D, D, 1.0f, 0);
    }
    // 7. sparse attention
    attn_sparse<<<N * B * H, 256, 0, stream>>>(qbuf, kbuf, vbuf, lens, attnb);
    // 8. output projection
    {
        dim3 g(D / BN, (Q * B + BM - 1) / BM);
        sgemm_nt<<<g, 256, 0, stream>>>(attnb, D, Wo, D, bo, nullptr, obuf, D,
                                        Q * B, D, D, 1.0f, 0);
    }
    // 9. residual add + mems clip (writes out region C)
    resid_clip<<<(Q * B * D / 4 + 255) / 256, 256, 0, stream>>>(
        obuf, rc, utt, result, out + (size_t)(T + R) * B * D);
    // 10. FFN input LN
    ln_kernel<<<RT * B, 256, 0, stream>>>(result, result, RT * B, ffln, nullptr,
                                          ffg, ffb, 0);
    // 11. FFN up + relu
    {
        dim3 g(FFN / BN, (RT * B + BM - 1) / BM);
        sgemm_nt<<<g, 256, 0, stream>>>(ffln, D, W1, D, b1, nullptr, ffh, FFN,
                                        RT * B, FFN, D, 1.0f, 1);
    }
    // 12. FFN down + residual
    {
        dim3 g(D / BN, (RT * B + BM - 1) / BM);
        sgemm_nt<<<g, 256, 0, stream>>>(ffh, FFN, W2, FFN, b2, result, res2, D,
                                        RT * B, D, FFN, 1.0f, 0);
    }
    // 13. output LN with row remap -> out regions A and B
    ln_kernel<<<RT * B, 256, 0, stream>>>(res2, res2, RT * B, out, nullptr,
                                          outg, outb, 1);
}

// Round 2
// 1106.025 us; speedup vs baseline: 2.3313x; 2.3313x over previous
//
#include <hip/hip_runtime.h>

// ---------------- problem constants ----------------
constexpr int D   = 1024;
constexpr int H   = 16;
constexpr int FFN = 4096;
constexpr int SEG = 128;
constexpr int L   = 32;
constexpr int RCL = 4;
constexpr int T   = 2048;
constexpr int B   = 2;
constexpr int N   = T / SEG;   // 16
constexpr int M   = N - 1;     // 15
constexpr int R   = RCL * N;   // 64
constexpr int Q   = R + T + N; // 2128
constexpr int KV  = M + R + T; // 2127
constexpr int RT  = R + T;     // 2112
constexpr float EPS = 1e-5f;

typedef float f32x4 __attribute__((ext_vector_type(4)));
typedef __bf16 bf16x8 __attribute__((ext_vector_type(8)));
typedef short s16x4 __attribute__((ext_vector_type(4)));

// ---------------- small helpers ----------------
__device__ inline void block_reduce_2(float& s1, float& s2) {
    #pragma unroll
    for (int off = 32; off > 0; off >>= 1) {
        s1 += __shfl_xor(s1, off, 64);
        s2 += __shfl_xor(s2, off, 64);
    }
    __shared__ float red[8];
    int lane = threadIdx.x & 63, w = threadIdx.x >> 6;
    if (lane == 0) { red[w * 2] = s1; red[w * 2 + 1] = s2; }
    __syncthreads();
    s1 = red[0] + red[2] + red[4] + red[6];
    s2 = red[1] + red[3] + red[5] + red[7];
}

// async global->LDS, 16B per lane; lds base must be wave-uniform
__device__ __forceinline__ void gload16(const void* g, void* l) {
    __builtin_amdgcn_global_load_lds(
        (__attribute__((address_space(1))) void*)(uintptr_t)g,
        (__attribute__((address_space(3))) void*)(unsigned)(uintptr_t)l,
        16, 0, 0);
}

// ---------------- float4 copy ----------------
__global__ __launch_bounds__(256) void copy4_kernel(const float* __restrict__ src,
                                                    float* __restrict__ dst, int n4) {
    int idx = blockIdx.x * 256 + threadIdx.x;
    if (idx < n4) {
        reinterpret_cast<float4*>(dst)[idx] = reinterpret_cast<const float4*>(src)[idx];
    }
}

// ---------------- LayerNorm (one block per row, D=1024) ----------------
__global__ __launch_bounds__(256) void ln_kernel(const float* __restrict__ src0,
                                                 const float* __restrict__ src1,
                                                 int split,
                                                 float* __restrict__ dst0,
                                                 float* __restrict__ dst1,
                                                 const float* __restrict__ gamma,
                                                 const float* __restrict__ beta,
                                                 int remap) {
    int row = blockIdx.x;
    int t = threadIdx.x;
    const float* src = (row < split) ? src0 + (size_t)row * D
                                     : src1 + (size_t)(row - split) * D;
    float4 x = *reinterpret_cast<const float4*>(&src[t * 4]);
    float s1 = x.x + x.y + x.z + x.w;
    float s2 = x.x * x.x + x.y * x.y + x.z * x.z + x.w * x.w;
    block_reduce_2(s1, s2);
    float mean = s1 * (1.0f / D);
    float var  = s2 * (1.0f / D) - mean * mean;
    float rs = rsqrtf(var + EPS);
    float4 g4 = *reinterpret_cast<const float4*>(&gamma[t * 4]);
    float4 b4 = *reinterpret_cast<const float4*>(&beta[t * 4]);
    float4 y;
    y.x = (x.x - mean) * rs * g4.x + b4.x;
    y.y = (x.y - mean) * rs * g4.y + b4.y;
    y.z = (x.z - mean) * rs * g4.z + b4.z;
    y.w = (x.w - mean) * rs * g4.w + b4.w;
    size_t off;
    if (!remap) {
        off = (size_t)row * D;
    } else {
        off = (row < R * B) ? ((size_t)T * B * D + (size_t)row * D)
                            : ((size_t)(row - R * B) * D);
    }
    *reinterpret_cast<float4*>(&dst0[off + t * 4]) = y;
    if (dst1) *reinterpret_cast<float4*>(&dst1[(size_t)row * D + t * 4]) = y;
}

// ---------------- summary (mean over SEG rows) ----------------
__global__ __launch_bounds__(256) void summary_kernel(float* __restrict__ qx) {
    int nb = blockIdx.x;          // N*B = 32
    int n = nb >> 1, b = nb & 1;
    int t = threadIdx.x;
    float4 acc = make_float4(0.f, 0.f, 0.f, 0.f);
    for (int s = 0; s < SEG; ++s) {
        size_t base = ((size_t)((R + n * SEG + s) * B + b)) * D + t * 4;
        float4 x = *reinterpret_cast<const float4*>(&qx[base]);
        acc.x += x.x; acc.y += x.y; acc.z += x.z; acc.w += x.w;
    }
    const float inv = 1.0f / SEG;
    acc.x *= inv; acc.y *= inv; acc.z *= inv; acc.w *= inv;
    size_t dst = ((size_t)(RT + n) * B + b) * D + t * 4;
    *reinterpret_cast<float4*>(&qx[dst]) = acc;
}

// ---------------- fp32 -> bf16 hi/lo split (exact residual), zero-pads M tail ----
__global__ __launch_bounds__(256) void split_bf16(const float* __restrict__ src,
                                                  ushort* __restrict__ hi,
                                                  ushort* __restrict__ lo,
                                                  int Mr, int kshift, int n4) {
    int idx = blockIdx.x * 256 + threadIdx.x;
    if (idx >= n4) return;
    int row = idx >> kshift;
    int c4 = idx & ((1 << kshift) - 1);
    size_t e = ((size_t)row << (kshift + 2)) + (size_t)c4 * 4;
    s16x4 h = {0, 0, 0, 0}, l = {0, 0, 0, 0};
    if (row < Mr) {
        float4 x = *reinterpret_cast<const float4*>(&src[e]);
        float xs[4] = {x.x, x.y, x.z, x.w};
        #pragma unroll
        for (int i = 0; i < 4; ++i) {
            unsigned u = __float_as_uint(xs[i]);
            unsigned hb = (u + 0x7FFFu + ((u >> 16) & 1u)) >> 16;
            float hf = __uint_as_float(hb << 16);
            float r = xs[i] - hf;                 // exact (Sterbenz)
            unsigned ur = __float_as_uint(r);
            unsigned lb = (ur + 0x7FFFu + ((ur >> 16) & 1u)) >> 16;
            h[i] = (short)hb;
            l[i] = (short)lb;
        }
    }
    *reinterpret_cast<s16x4*>(&hi[e]) = h;
    *reinterpret_cast<s16x4*>(&lo[e]) = l;
}

// ---------------- split-bf16 MFMA GEMM ----------------
// C[m][n] = (sum_k A[m][k]*W[n][k] + bias[n]) * alpha  (+relu) (+residual)
// A as hi/lo bf16 [Mpad][Kd] row-major (M padded to 128, zeros);
// W as hi/lo bf16 [Nc][Kd]. 128x128 tile, BK=32, 4 waves 2x2, m97 structure.
__global__ __launch_bounds__(256) void gemm_split(const ushort* __restrict__ Ah,
                                                  const ushort* __restrict__ Al,
                                                  const ushort* __restrict__ Wh,
                                                  const ushort* __restrict__ Wl,
                                                  const float* __restrict__ bias,
                                                  const float* __restrict__ residual,
                                                  float* __restrict__ C,
                                                  int Mr, int Nc, int Kd,
                                                  float alpha, int do_relu) {
    __shared__ __align__(16) ushort sm[4 * 4096];   // Ah | Al | Wh | Wl (32 KB)
    ushort* sAh = sm;
    ushort* sAl = sm + 4096;
    ushort* sWh = sm + 8192;
    ushort* sWl = sm + 12288;

    const int t = threadIdx.x;
    const int w = t >> 6, lane = t & 63;
    const int wr = w >> 1, wc = w & 1;
    const int fr = lane & 15, fq = lane >> 4;
    const int bn0 = blockIdx.x * 128;
    const int bm0 = blockIdx.y * 128;

    // staging: wave w owns chunks {2w, 2w+1} (16 rows each) of every matrix
    const int srow = lane >> 2;
    const int scol = (lane & 3) * 8;
    const size_t aR0 = (size_t)(bm0 + w * 32 + srow) * Kd + scol;
    const size_t aR1 = aR0 + (size_t)16 * Kd;
    const size_t wR0 = (size_t)(bn0 + w * 32 + srow) * Kd + scol;
    const size_t wR1 = wR0 + (size_t)16 * Kd;
    const int lbase = w * 1024;   // elem offset of chunk 2w in each LDS matrix

    f32x4 acc[4][4];
    #pragma unroll
    for (int m = 0; m < 4; ++m)
        #pragma unroll
        for (int n = 0; n < 4; ++n) acc[m][n] = f32x4{0.f, 0.f, 0.f, 0.f};

    const int ao = (wr * 64 + fr) * 32 + fq * 8;
    const int wo = (wc * 64 + fr) * 32 + fq * 8;

    for (int k0 = 0; k0 < Kd; k0 += 32) {
        gload16(Ah + aR0 + k0, sAh + lbase);
        gload16(Ah + aR1 + k0, sAh + lbase + 512);
        gload16(Al + aR0 + k0, sAl + lbase);
        gload16(Al + aR1 + k0, sAl + lbase + 512);
        gload16(Wh + wR0 + k0, sWh + lbase);
        gload16(Wh + wR1 + k0, sWh + lbase + 512);
        gload16(Wl + wR0 + k0, sWl + lbase);
        gload16(Wl + wR1 + k0, sWl + lbase + 512);
        __syncthreads();   // compiler drains vmcnt before barrier

        bf16x8 bh[4], bl[4];
        #pragma unroll
        for (int n = 0; n < 4; ++n) {
            bh[n] = *reinterpret_cast<const bf16x8*>(&sWh[wo + n * 512]);
            bl[n] = *reinterpret_cast<const bf16x8*>(&sWl[wo + n * 512]);
        }
        #pragma unroll
        for (int m = 0; m < 4; ++m) {
            bf16x8 ah = *reinterpret_cast<const bf16x8*>(&sAh[ao + m * 512]);
            bf16x8 al = *reinterpret_cast<const bf16x8*>(&sAl[ao + m * 512]);
            #pragma unroll
            for (int n = 0; n < 4; ++n) {
                acc[m][n] = __builtin_amdgcn_mfma_f32_16x16x32_bf16(ah, bh[n], acc[m][n], 0, 0, 0);
                acc[m][n] = __builtin_amdgcn_mfma_f32_16x16x32_bf16(ah, bl[n], acc[m][n], 0, 0, 0);
                acc[m][n] = __builtin_amdgcn_mfma_f32_16x16x32_bf16(al, bh[n], acc[m][n], 0, 0, 0);
            }
        }
        __syncthreads();
    }

    // epilogue: C/D layout col=lane&15, row=(lane>>4)*4+j  [m89-verified]
    float bv[4];
    #pragma unroll
    for (int n = 0; n < 4; ++n) bv[n] = bias[bn0 + wc * 64 + n * 16 + fr];
    #pragma unroll
    for (int m = 0; m < 4; ++m) {
        #pragma unroll
        for (int j = 0; j < 4; ++j) {
            int row = bm0 + wr * 64 + m * 16 + fq * 4 + j;
            if (row < Mr) {
                #pragma unroll
                for (int n = 0; n < 4; ++n) {
                    int col = bn0 + wc * 64 + n * 16 + fr;
                    float v = (acc[m][n][j] + bv[n]) * alpha;
                    if (do_relu) v = fmaxf(v, 0.f);
                    if (residual) v += residual[(size_t)row * Nc + col];
                    C[(size_t)row * Nc + col] = v;
                }
            }
        }
    }
}

// ---------------- sparse masked attention (unchanged from r1, passed) ----------
constexpr int CMAX = 192;
constexpr int KTS  = 193;

__global__ __launch_bounds__(256) void attn_sparse(const float* __restrict__ qb,
                                                   const float* __restrict__ kb,
                                                   const float* __restrict__ vb,
                                                   const int* __restrict__ lengths,
                                                   float* __restrict__ attn) {
    __shared__ __align__(16) float Kt[64 * KTS];
    __shared__ __align__(16) float Vt[CMAX * 64];
    __shared__ __align__(16) float qs[4][64];
    __shared__ __align__(16) float ps[4][192];
    __shared__ int colmap[CMAX];

    int gid = blockIdx.x;
    int i  = gid & 15;
    int bh = gid >> 4;
    int b  = bh >> 4;
    int h  = bh & 15;
    int t = threadIdx.x;
    int lane = t & 63, w = t >> 6;

    int nm = i;
    int u0 = (i * SEG - L > 0) ? (i * SEG - L) : 0;
    int nu = (i + 1) * SEG - u0;
    int nc = nm + RCL + nu;

    int maxlen = max(lengths[0], lengths[1]);
    int kl = lengths[b] + (M + R + T) - maxlen;

    for (int c = t; c < nc; c += 256) {
        int g;
        if (c < nm)            g = c;
        else if (c < nm + RCL) g = M + i * RCL + (c - nm);
        else                   g = M + R + u0 + (c - nm - RCL);
        colmap[c] = g;
    }
    __syncthreads();

    for (int f = t; f < nc * 16; f += 256) {
        int c = f >> 4, dc = f & 15;
        int g = colmap[c];
        size_t base = ((size_t)g * B + b) * D + h * 64 + dc * 4;
        float4 k4 = *reinterpret_cast<const float4*>(&kb[base]);
        Kt[(dc * 4 + 0) * KTS + c] = k4.x;
        Kt[(dc * 4 + 1) * KTS + c] = k4.y;
        Kt[(dc * 4 + 2) * KTS + c] = k4.z;
        Kt[(dc * 4 + 3) * KTS + c] = k4.w;
        float4 v4 = *reinterpret_cast<const float4*>(&vb[base]);
        *reinterpret_cast<float4*>(&Vt[c * 64 + dc * 4]) = v4;
    }
    __syncthreads();

    const int nrow = RCL + SEG + 1;   // 133 query rows per group
    for (int r = w; r < nrow; r += 4) {
        int qrow;
        if (r < RCL)            qrow = i * RCL + r;
        else if (r < RCL + SEG) qrow = R + i * SEG + (r - RCL);
        else                    qrow = R + T + i;

        qs[w][lane] = qb[((size_t)qrow * B + b) * D + h * 64 + lane];

        int c0 = lane, c1 = lane + 64, c2 = lane + 128;
        float a0 = 0.f, a1 = 0.f, a2 = 0.f;
        #pragma unroll
        for (int d = 0; d < 64; d += 4) {
            float4 qv = *reinterpret_cast<const float4*>(&qs[w][d]);
            a0 += qv.x * Kt[(d + 0) * KTS + c0] + qv.y * Kt[(d + 1) * KTS + c0]
                + qv.z * Kt[(d + 2) * KTS + c0] + qv.w * Kt[(d + 3) * KTS + c0];
            a1 += qv.x * Kt[(d + 0) * KTS + c1] + qv.y * Kt[(d + 1) * KTS + c1]
                + qv.z * Kt[(d + 2) * KTS + c1] + qv.w * Kt[(d + 3) * KTS + c1];
            a2 += qv.x * Kt[(d + 0) * KTS + c2] + qv.y * Kt[(d + 1) * KTS + c2]
                + qv.z * Kt[(d + 2) * KTS + c2] + qv.w * Kt[(d + 3) * KTS + c2];
        }
        bool v0 = (c0 < nc) && (colmap[c0] < kl);
        bool v1 = (c1 < nc) && (colmap[c1] < kl);
        bool v2 = (c2 < nc) && (colmap[c2] < kl);
        float s0 = v0 ? a0 : -1e30f;
        float s1 = v1 ? a1 : -1e30f;
        float s2 = v2 ? a2 : -1e30f;

        float m = fmaxf(fmaxf(s0, s1), s2);
        #pragma unroll
        for (int off = 32; off > 0; off >>= 1) m = fmaxf(m, __shfl_xor(m, off, 64));

        float p0 = __expf(s0 - m), p1 = __expf(s1 - m), p2 = __expf(s2 - m);
        float sum = p0 + p1 + p2;
        #pragma unroll
        for (int off = 32; off > 0; off >>= 1) sum += __shfl_xor(sum, off, 64);

        ps[w][c0] = p0; ps[w][c1] = p1; ps[w][c2] = p2;

        float o = 0.f;
        int c = 0;
        for (; c + 4 <= nc; c += 4) {
            o += ps[w][c + 0] * Vt[(c + 0) * 64 + lane]
               + ps[w][c + 1] * Vt[(c + 1) * 64 + lane]
               + ps[w][c + 2] * Vt[(c + 2) * 64 + lane]
               + ps[w][c + 3] * Vt[(c + 3) * 64 + lane];
        }
        for (; c < nc; ++c) o += ps[w][c] * Vt[c * 64 + lane];

        attn[((size_t)qrow * B + b) * D + h * 64 + lane] = o / sum;
    }
}

// ---------------- residual add + mems clip ----------------
__global__ __launch_bounds__(256) void resid_clip(const float* __restrict__ obuf,
                                                  const float* __restrict__ rc,
                                                  const float* __restrict__ utt,
                                                  float* __restrict__ result,
                                                  float* __restrict__ out_mems) {
    size_t idx = (size_t)blockIdx.x * 256 + threadIdx.x;
    size_t f = idx * 4;
    if (f >= (size_t)Q * B * D) return;
    int row = (int)(f >> 10);
    float4 o = *reinterpret_cast<const float4*>(&obuf[f]);
    if (row < RT * B) {
        const float* res = (row < R * B) ? &rc[f] : &utt[f - (size_t)R * B * D];
        float4 rv = *reinterpret_cast<const float4*>(res);
        o.x += rv.x; o.y += rv.y; o.z += rv.z; o.w += rv.w;
        *reinterpret_cast<float4*>(&result[f]) = o;
    } else {
        o.x = fminf(fmaxf(o.x, -10.f), 10.f);
        o.y = fminf(fmaxf(o.y, -10.f), 10.f);
        o.z = fminf(fmaxf(o.z, -10.f), 10.f);
        o.w = fminf(fmaxf(o.w, -10.f), 10.f);
        *reinterpret_cast<float4*>(&out_mems[f - (size_t)RT * B * D]) = o;
    }
}

// ---------------- launch ----------------
extern "C" void kernel_launch(void* const* d_in, const int* in_sizes, int n_in,
                              void* d_out, int out_size, void* d_ws, size_t ws_size,
                              hipStream_t stream) {
    const float* utt   = (const float*)d_in[0];
    const float* rc    = (const float*)d_in[1];
    const float* mems  = (const float*)d_in[2];
    const float* lng   = (const float*)d_in[3];
    const float* lnb   = (const float*)d_in[4];
    const float* Wq    = (const float*)d_in[5];
    const float* bq    = (const float*)d_in[6];
    const float* Wkv   = (const float*)d_in[7];
    const float* bkv   = (const float*)d_in[8];
    const float* Wo    = (const float*)d_in[9];
    const float* bo    = (const float*)d_in[10];
    const float* ffg   = (const float*)d_in[11];
    const float* ffb   = (const float*)d_in[12];
    const float* W1    = (const float*)d_in[13];
    const float* b1    = (const float*)d_in[14];
    const float* W2    = (const float*)d_in[15];
    const float* b2    = (const float*)d_in[16];
    const float* outg  = (const float*)d_in[17];
    const float* outb  = (const float*)d_in[18];
    const int*   lens  = (const int*)d_in[19];

    constexpr int QBD  = Q * B * D;     // 4,358,144
    constexpr int KVBD = KV * B * D;    // 4,356,096
    constexpr int FFH  = RT * B * FFN;  // 17,301,504
    constexpr int MPAD = 4352;          // ceil(4256/128)*128

    float* ws = (float*)d_ws;
    size_t off = 0;
    auto alloc = [&](size_t n) { float* p = ws + off; off += (n + 63) & ~(size_t)63; return p; };
    float* f_qx  = alloc(QBD);
    float* f_kvx = alloc(KVBD);
    float* f_q   = alloc(QBD);
    float* f_k   = alloc(KVBD);
    float* f_v   = alloc(KVBD);
    float* f_ffh = alloc(FFH);
    ushort* actH = (ushort*)alloc(FFH / 2);      // max activation: 4224x4096 bf16
    ushort* actL = (ushort*)alloc(FFH / 2);
    ushort* wH   = (ushort*)alloc(FFN * D / 2);  // max weight: 4096x1024 bf16
    ushort* wL   = (ushort*)alloc(FFN * D / 2);
    // aliases (stream-ordered lifetimes verified):
    float* attnb  = f_qx;    // after f_qx converted
    float* obuf   = f_q;     // after attention read f_q
    float* result = f_kvx;   // after f_kvx converted
    float* ffln   = f_q;     // after resid_clip read obuf
    float* res2   = f_qx;    // after attnb converted
    float* out = (float*)d_out;

    auto conv = [&](const float* src, ushort* h, ushort* l, int Mr, int Mpad, int Kd) {
        int kshift = (Kd == 1024) ? 8 : 10;
        int n4 = Mpad * (Kd >> 2);
        split_bf16<<<(n4 + 255) / 256, 256, 0, stream>>>(src, h, l, Mr, kshift, n4);
    };
    auto gemm = [&](const ushort* ah, const ushort* al, const ushort* whp, const ushort* wlp,
                    const float* bias, const float* resid, float* C,
                    int Mr, int Mpad, int Nc, int Kd, float alpha, int relu) {
        dim3 g(Nc / 128, Mpad / 128);
        gemm_split<<<g, 256, 0, stream>>>(ah, al, whp, wlp, bias, resid, C,
                                          Mr, Nc, Kd, alpha, relu);
    };

    // 1. mems -> f_kvx[0:M*B)
    copy4_kernel<<<(M * B * D / 4 + 255) / 256, 256, 0, stream>>>(mems, f_kvx, M * B * D / 4);
    // 2. input LN -> f_qx rows [0,RT*B) and f_kvx rows [M*B,..)
    ln_kernel<<<RT * B, 256, 0, stream>>>(rc, utt, R * B, f_qx, f_kvx + (size_t)M * B * D,
                                          lng, lnb, 0);
    // 3. summary -> f_qx rows [RT*B, Q*B)
    summary_kernel<<<N * B, 256, 0, stream>>>(f_qx);
    // 4. q projection
    conv(f_qx, actH, actL, Q * B, MPAD, D);
    conv(Wq, wH, wL, D, D, D);
    gemm(actH, actL, wH, wL, bq, nullptr, f_q, Q * B, MPAD, D, D, 0.125f, 0);
    // 5/6. k and v projections
    conv(f_kvx, actH, actL, KV * B, MPAD, D);
    conv(Wkv, wH, wL, D, D, D);
    gemm(actH, actL, wH, wL, bkv, nullptr, f_k, KV * B, MPAD, D, D, 1.0f, 0);
    conv(Wkv + (size_t)D * D, wH, wL, D, D, D);
    gemm(actH, actL, wH, wL, bkv + D, nullptr, f_v, KV * B, MPAD, D, D, 1.0f, 0);
    // 7. sparse attention -> attnb (= f_qx)
    attn_sparse<<<N * B * H, 256, 0, stream>>>(f_q, f_k, f_v, lens, attnb);
    // 8. output projection -> obuf (= f_q)
    conv(attnb, actH, actL, Q * B, MPAD, D);
    conv(Wo, wH, wL, D, D, D);
    gemm(actH, actL, wH, wL, bo, nullptr, obuf, Q * B, MPAD, D, D, 1.0f, 0);
    // 9. residual + mems clip
    resid_clip<<<(Q * B * D / 4 + 255) / 256, 256, 0, stream>>>(
        obuf, rc, utt, result, out + (size_t)(T + R) * B * D);
    // 10. FFN input LN -> ffln (= f_q)
    ln_kernel<<<RT * B, 256, 0, stream>>>(result, result, RT * B, ffln, nullptr,
                                          ffg, ffb, 0);
    // 11. FFN up + relu -> f_ffh
    conv(ffln, actH, actL, RT * B, RT * B, D);
    conv(W1, wH, wL, FFN, FFN, D);
    gemm(actH, actL, wH, wL, b1, nullptr, f_ffh, RT * B, RT * B, FFN, D, 1.0f, 1);
    // 12. FFN down + residual -> res2 (= f_qx)
    conv(f_ffh, actH, actL, RT * B, RT * B, FFN);
    conv(W2, wH, wL, D, D, FFN);
    gemm(actH, actL, wH, wL, b2, result, res2, RT * B, RT * B, D, FFN, 1.0f, 0);
    // 13. output LN with row remap -> out
    ln_kernel<<<RT * B, 256, 0, stream>>>(res2, res2, RT * B, out, nullptr,
                                          outg, outb, 1);
}

// Round 5
// 934.629 us; speedup vs baseline: 2.7588x; 1.1834x over previous
//
#include <hip/hip_runtime.h>

// ---------------- problem constants ----------------
constexpr int D   = 1024;
constexpr int H   = 16;
constexpr int FFN = 4096;
constexpr int SEG = 128;
constexpr int L   = 32;
constexpr int RCL = 4;
constexpr int T   = 2048;
constexpr int B   = 2;
constexpr int N   = T / SEG;   // 16
constexpr int M   = N - 1;     // 15
constexpr int R   = RCL * N;   // 64
constexpr int Q   = R + T + N; // 2128
constexpr int KV  = M + R + T; // 2127
constexpr int RT  = R + T;     // 2112
constexpr float EPS = 1e-5f;
constexpr int MPAD = 4352;     // ceil(4256/128)*128

typedef float f32x4 __attribute__((ext_vector_type(4)));
typedef __bf16 bf16x8 __attribute__((ext_vector_type(8)));
typedef short s16x4 __attribute__((ext_vector_type(4)));

// ---------------- helpers ----------------
__device__ __forceinline__ ushort bf16rne(float x) {
    unsigned u = __float_as_uint(x);
    return (ushort)((u + 0x7FFFu + ((u >> 16) & 1u)) >> 16);
}
__device__ __forceinline__ void split1(float x, ushort& h, ushort& l) {
    unsigned u = __float_as_uint(x);
    unsigned hb = (u + 0x7FFFu + ((u >> 16) & 1u)) >> 16;
    float hf = __uint_as_float(hb << 16);
    float r = x - hf;                       // exact residual
    unsigned ur = __float_as_uint(r);
    h = (ushort)hb;
    l = (ushort)((ur + 0x7FFFu + ((ur >> 16) & 1u)) >> 16);
}
__device__ __forceinline__ float bf2f(ushort h) {
    return __uint_as_float(((unsigned)h) << 16);
}

__device__ inline void block_reduce_2(float& s1, float& s2) {
    #pragma unroll
    for (int off = 32; off > 0; off >>= 1) {
        s1 += __shfl_xor(s1, off, 64);
        s2 += __shfl_xor(s2, off, 64);
    }
    __shared__ float red[8];
    int lane = threadIdx.x & 63, w = threadIdx.x >> 6;
    if (lane == 0) { red[w * 2] = s1; red[w * 2 + 1] = s2; }
    __syncthreads();
    s1 = red[0] + red[2] + red[4] + red[6];
    s2 = red[1] + red[3] + red[5] + red[7];
}

// async global->LDS, 16B per lane; lds base must be wave-uniform
__device__ __forceinline__ void gload16(const void* g, void* l) {
    __builtin_amdgcn_global_load_lds(
        (__attribute__((address_space(1))) void*)(uintptr_t)g,
        (__attribute__((address_space(3))) void*)(unsigned)(uintptr_t)l,
        16, 0, 0);
}

// ---------------- zero-pad bf16 pad rows ----------------
__global__ __launch_bounds__(256) void zpad_kernel(ushort* __restrict__ Hp,
                                                   ushort* __restrict__ Lp, int n4) {
    int idx = blockIdx.x * 256 + threadIdx.x;
    if (idx < n4) {
        s16x4 z = {0, 0, 0, 0};
        *reinterpret_cast<s16x4*>(&Hp[(size_t)idx * 4]) = z;
        *reinterpret_cast<s16x4*>(&Lp[(size_t)idx * 4]) = z;
    }
}

// ---------------- LayerNorm with fused bf16 hi/lo split outputs ----------------
__global__ __launch_bounds__(256) void ln2_kernel(const float* __restrict__ src0,
                                                  const float* __restrict__ src1,
                                                  int split,
                                                  float* __restrict__ dstF, int remap,
                                                  ushort* __restrict__ H0,
                                                  ushort* __restrict__ L0,
                                                  ushort* __restrict__ H1,
                                                  ushort* __restrict__ L1,
                                                  int rowoff1,
                                                  const float* __restrict__ gamma,
                                                  const float* __restrict__ beta) {
    int row = blockIdx.x;
    int t = threadIdx.x;
    const float* src = (row < split) ? src0 + (size_t)row * D
                                     : src1 + (size_t)(row - split) * D;
    float4 x = *reinterpret_cast<const float4*>(&src[t * 4]);
    float s1 = x.x + x.y + x.z + x.w;
    float s2 = x.x * x.x + x.y * x.y + x.z * x.z + x.w * x.w;
    block_reduce_2(s1, s2);
    float mean = s1 * (1.0f / D);
    float var  = s2 * (1.0f / D) - mean * mean;
    float rs = rsqrtf(var + EPS);
    float4 g4 = *reinterpret_cast<const float4*>(&gamma[t * 4]);
    float4 b4 = *reinterpret_cast<const float4*>(&beta[t * 4]);
    float y[4];
    y[0] = (x.x - mean) * rs * g4.x + b4.x;
    y[1] = (x.y - mean) * rs * g4.y + b4.y;
    y[2] = (x.z - mean) * rs * g4.z + b4.z;
    y[3] = (x.w - mean) * rs * g4.w + b4.w;
    if (dstF) {
        size_t off;
        if (!remap) off = (size_t)row * D;
        else off = (row < R * B) ? ((size_t)T * B * D + (size_t)row * D)
                                 : ((size_t)(row - R * B) * D);
        *reinterpret_cast<float4*>(&dstF[off + t * 4]) =
            make_float4(y[0], y[1], y[2], y[3]);
    }
    if (H0) {
        s16x4 h4, l4;
        #pragma unroll
        for (int j = 0; j < 4; ++j) {
            ushort hh, ll; split1(y[j], hh, ll);
            h4[j] = (short)hh; l4[j] = (short)ll;
        }
        size_t o0 = (size_t)row * D + t * 4;
        *reinterpret_cast<s16x4*>(&H0[o0]) = h4;
        *reinterpret_cast<s16x4*>(&L0[o0]) = l4;
        if (H1) {
            size_t o1 = (size_t)(row + rowoff1) * D + t * 4;
            *reinterpret_cast<s16x4*>(&H1[o1]) = h4;
            *reinterpret_cast<s16x4*>(&L1[o1]) = l4;
        }
    }
}

// ---------------- summary (mean over SEG rows, fp32 source) -> bf16 split ------
__global__ __launch_bounds__(256) void summary3_kernel(const float* __restrict__ qxF,
                                                       ushort* __restrict__ qxH,
                                                       ushort* __restrict__ qxL) {
    int nb = blockIdx.x;          // N*B = 32
    int n = nb >> 1, b = nb & 1;
    int t = threadIdx.x;
    float acc[4] = {0.f, 0.f, 0.f, 0.f};
    for (int s = 0; s < SEG; ++s) {
        size_t base = ((size_t)((R + n * SEG + s) * B + b)) * D + t * 4;
        float4 x = *reinterpret_cast<const float4*>(&qxF[base]);
        acc[0] += x.x; acc[1] += x.y; acc[2] += x.z; acc[3] += x.w;
    }
    s16x4 h4, l4;
    #pragma unroll
    for (int j = 0; j < 4; ++j) {
        ushort hh, ll; split1(acc[j] * (1.0f / SEG), hh, ll);
        h4[j] = (short)hh; l4[j] = (short)ll;
    }
    size_t dst = ((size_t)(RT * B + nb)) * D + t * 4;
    *reinterpret_cast<s16x4*>(&qxH[dst]) = h4;
    *reinterpret_cast<s16x4*>(&qxL[dst]) = l4;
}

// ---------------- fp32 -> bf16 hi/lo split (weights + mems) ----------------
__global__ __launch_bounds__(256) void split_bf16(const float* __restrict__ src,
                                                  ushort* __restrict__ hi,
                                                  ushort* __restrict__ lo,
                                                  int Mr, int kshift, int n4) {
    int idx = blockIdx.x * 256 + threadIdx.x;
    if (idx >= n4) return;
    int row = idx >> kshift;
    int c4 = idx & ((1 << kshift) - 1);
    size_t e = ((size_t)row << (kshift + 2)) + (size_t)c4 * 4;
    s16x4 h = {0, 0, 0, 0}, l = {0, 0, 0, 0};
    if (row < Mr) {
        float4 x = *reinterpret_cast<const float4*>(&src[e]);
        float xs[4] = {x.x, x.y, x.z, x.w};
        #pragma unroll
        for (int i = 0; i < 4; ++i) {
            ushort hh, ll; split1(xs[i], hh, ll);
            h[i] = (short)hh; l[i] = (short)ll;
        }
    }
    *reinterpret_cast<s16x4*>(&hi[e]) = h;
    *reinterpret_cast<s16x4*>(&lo[e]) = l;
}

// ---------------- split-bf16 MFMA GEMM (m97 structure, 128x128, BK=32) --------
__global__ __launch_bounds__(256) void gemm_split(const ushort* __restrict__ Ah,
                                                  const ushort* __restrict__ Al,
                                                  const ushort* __restrict__ Wh,
                                                  const ushort* __restrict__ Wl,
                                                  const float* __restrict__ bias,
                                                  const float* __restrict__ residual,
                                                  float* __restrict__ C,
                                                  ushort* __restrict__ CH,
                                                  ushort* __restrict__ CL,
                                                  int Mr, int Nc, int Kd,
                                                  float alpha, int do_relu) {
    __shared__ __align__(16) ushort sm[4 * 4096];   // Ah | Al | Wh | Wl (32 KB)
    ushort* sAh = sm;
    ushort* sAl = sm + 4096;
    ushort* sWh = sm + 8192;
    ushort* sWl = sm + 12288;

    const int t = threadIdx.x;
    const int w = t >> 6, lane = t & 63;
    const int wr = w >> 1, wc = w & 1;
    const int fr = lane & 15, fq = lane >> 4;
    const int bn0 = blockIdx.x * 128;
    const int bm0 = blockIdx.y * 128;

    const int srow = lane >> 2;
    const int scol = (lane & 3) * 8;
    const size_t aR0 = (size_t)(bm0 + w * 32 + srow) * Kd + scol;
    const size_t aR1 = aR0 + (size_t)16 * Kd;
    const size_t wR0 = (size_t)(bn0 + w * 32 + srow) * Kd + scol;
    const size_t wR1 = wR0 + (size_t)16 * Kd;
    const int lbase = w * 1024;

    f32x4 acc[4][4];
    #pragma unroll
    for (int m = 0; m < 4; ++m)
        #pragma unroll
        for (int n = 0; n < 4; ++n) acc[m][n] = f32x4{0.f, 0.f, 0.f, 0.f};

    const int ao = (wr * 64 + fr) * 32 + fq * 8;
    const int wo = (wc * 64 + fr) * 32 + fq * 8;

    for (int k0 = 0; k0 < Kd; k0 += 32) {
        gload16(Ah + aR0 + k0, sAh + lbase);
        gload16(Ah + aR1 + k0, sAh + lbase + 512);
        gload16(Al + aR0 + k0, sAl + lbase);
        gload16(Al + aR1 + k0, sAl + lbase + 512);
        gload16(Wh + wR0 + k0, sWh + lbase);
        gload16(Wh + wR1 + k0, sWh + lbase + 512);
        gload16(Wl + wR0 + k0, sWl + lbase);
        gload16(Wl + wR1 + k0, sWl + lbase + 512);
        __syncthreads();

        bf16x8 bh[4], bl[4];
        #pragma unroll
        for (int n = 0; n < 4; ++n) {
            bh[n] = *reinterpret_cast<const bf16x8*>(&sWh[wo + n * 512]);
            bl[n] = *reinterpret_cast<const bf16x8*>(&sWl[wo + n * 512]);
        }
        #pragma unroll
        for (int m = 0; m < 4; ++m) {
            bf16x8 ah = *reinterpret_cast<const bf16x8*>(&sAh[ao + m * 512]);
            bf16x8 al = *reinterpret_cast<const bf16x8*>(&sAl[ao + m * 512]);
            #pragma unroll
            for (int n = 0; n < 4; ++n) {
                acc[m][n] = __builtin_amdgcn_mfma_f32_16x16x32_bf16(ah, bh[n], acc[m][n], 0, 0, 0);
                acc[m][n] = __builtin_amdgcn_mfma_f32_16x16x32_bf16(ah, bl[n], acc[m][n], 0, 0, 0);
                acc[m][n] = __builtin_amdgcn_mfma_f32_16x16x32_bf16(al, bh[n], acc[m][n], 0, 0, 0);
            }
        }
        __syncthreads();
    }

    float bv[4];
    #pragma unroll
    for (int n = 0; n < 4; ++n) bv[n] = bias[bn0 + wc * 64 + n * 16 + fr];
    #pragma unroll
    for (int m = 0; m < 4; ++m) {
        #pragma unroll
        for (int j = 0; j < 4; ++j) {
            int row = bm0 + wr * 64 + m * 16 + fq * 4 + j;
            if (row < Mr) {
                #pragma unroll
                for (int n = 0; n < 4; ++n) {
                    int col = bn0 + wc * 64 + n * 16 + fr;
                    float v = (acc[m][n][j] + bv[n]) * alpha;
                    if (do_relu) v = fmaxf(v, 0.f);
                    if (residual) v += residual[(size_t)row * Nc + col];
                    if (CH) {
                        ushort hh, ll; split1(v, hh, ll);
                        CH[(size_t)row * Nc + col] = hh;
                        CL[(size_t)row * Nc + col] = ll;
                    } else {
                        C[(size_t)row * Nc + col] = v;
                    }
                }
            }
        }
    }
}

// ---------------- sparse masked attention v2 (r3 body, exonerated) ----------
// 1024 blocks = (b,h,i,half). K fp32 in LDS [64][KTS]; V bf16 in LDS [64][CST];
// 2 q-rows per wave-iteration; output written as bf16 hi/lo split.
// NOTE: Kt reads at c2 up to 191 exceed KTS=181 row extent; they stay inside
// the LDS allocation and are masked by v2=(c2<nc) -> harmless by design.
constexpr int KTS = 181;   // fp32 K stride (odd -> conflict-free lane-per-col)
constexpr int CST = 186;   // bf16 V stride (CST/2=93 coprime 32 -> 2 lanes/bank)
constexpr int CMX = 192;

__global__ __launch_bounds__(256) void attn2(const float* __restrict__ qb,
                                             const float* __restrict__ kb,
                                             const float* __restrict__ vb,
                                             const int* __restrict__ lengths,
                                             ushort* __restrict__ outH,
                                             ushort* __restrict__ outL) {
    __shared__ __align__(16) float  Kt[64 * KTS];     // 46336 B
    __shared__ __align__(16) ushort Vt[64 * CST];     // 23808 B
    __shared__ __align__(16) float  ps[4][2][CMX];    // 6144 B
    __shared__ __align__(16) float  qs[4][2][64];     // 2048 B
    __shared__ int colmap[CMX];                       // 768 B  -> ~77.3 KB (2 blk/CU)

    int gid = blockIdx.x;
    int half = gid & 1;
    int i = (gid >> 1) & 15;
    int h = (gid >> 5) & 15;
    int b = gid >> 9;
    int t = threadIdx.x;
    int lane = t & 63, w = t >> 6;

    int nm = i;
    int u0 = (i * SEG - L > 0) ? (i * SEG - L) : 0;
    int nc = nm + RCL + (i + 1) * SEG - u0;

    int maxlen = max(lengths[0], lengths[1]);
    int kl = lengths[b] + (M + R + T) - maxlen;

    for (int c = t; c < nc; c += 256) {
        int g;
        if (c < nm)            g = c;
        else if (c < nm + RCL) g = M + i * RCL + (c - nm);
        else                   g = M + R + u0 + (c - nm - RCL);
        colmap[c] = g;
    }
    __syncthreads();

    for (int f = t; f < nc * 16; f += 256) {
        int c = f >> 4, dc = f & 15;
        int g = colmap[c];
        size_t base = ((size_t)g * B + b) * D + h * 64 + dc * 4;
        float4 k4 = *reinterpret_cast<const float4*>(&kb[base]);
        Kt[(dc * 4 + 0) * KTS + c] = k4.x;
        Kt[(dc * 4 + 1) * KTS + c] = k4.y;
        Kt[(dc * 4 + 2) * KTS + c] = k4.z;
        Kt[(dc * 4 + 3) * KTS + c] = k4.w;
        float4 v4 = *reinterpret_cast<const float4*>(&vb[base]);
        Vt[(dc * 4 + 0) * CST + c] = bf16rne(v4.x);
        Vt[(dc * 4 + 1) * CST + c] = bf16rne(v4.y);
        Vt[(dc * 4 + 2) * CST + c] = bf16rne(v4.z);
        Vt[(dc * 4 + 3) * CST + c] = bf16rne(v4.w);
    }
    __syncthreads();

    const int nrows = half ? 65 : 68;
    const int rbase = half ? 68 : 0;
    const int c0 = lane, c1 = lane + 64, c2 = lane + 128;
    bool v0 = (c0 < nc) && (colmap[c0] < kl);
    bool v1 = (c1 < nc) && (colmap[c1] < kl);
    bool v2 = (c2 < nc) && (colmap[c2] < kl);

    for (int rl = w * 2; rl < nrows; rl += 8) {
        int r0 = rbase + rl;
        bool two = (rl + 1 < nrows);
        int r1 = two ? r0 + 1 : r0;
        int qrow0 = (r0 < RCL) ? i * RCL + r0
                  : (r0 < 132) ? R + i * SEG + (r0 - RCL)
                               : R + T + i;
        int qrow1 = (r1 < RCL) ? i * RCL + r1
                  : (r1 < 132) ? R + i * SEG + (r1 - RCL)
                               : R + T + i;

        qs[w][0][lane] = qb[((size_t)qrow0 * B + b) * D + h * 64 + lane];
        qs[w][1][lane] = qb[((size_t)qrow1 * B + b) * D + h * 64 + lane];
        asm volatile("" ::: "memory");

        float a00 = 0.f, a01 = 0.f, a02 = 0.f;
        float a10 = 0.f, a11 = 0.f, a12 = 0.f;
        #pragma unroll
        for (int d = 0; d < 64; d += 4) {
            float4 q0 = *reinterpret_cast<const float4*>(&qs[w][0][d]);
            float4 q1 = *reinterpret_cast<const float4*>(&qs[w][1][d]);
            #pragma unroll
            for (int dd = 0; dd < 4; ++dd) {
                float k0 = Kt[(d + dd) * KTS + c0];
                float k1 = Kt[(d + dd) * KTS + c1];
                float k2 = Kt[(d + dd) * KTS + c2];
                float qa = (dd == 0) ? q0.x : (dd == 1) ? q0.y : (dd == 2) ? q0.z : q0.w;
                float qbv = (dd == 0) ? q1.x : (dd == 1) ? q1.y : (dd == 2) ? q1.z : q1.w;
                a00 += qa * k0;  a01 += qa * k1;  a02 += qa * k2;
                a10 += qbv * k0; a11 += qbv * k1; a12 += qbv * k2;
            }
        }
        float s00 = v0 ? a00 : -1e30f, s01 = v1 ? a01 : -1e30f, s02 = v2 ? a02 : -1e30f;
        float s10 = v0 ? a10 : -1e30f, s11 = v1 ? a11 : -1e30f, s12 = v2 ? a12 : -1e30f;

        float m0 = fmaxf(fmaxf(s00, s01), s02);
        float m1 = fmaxf(fmaxf(s10, s11), s12);
        #pragma unroll
        for (int off = 32; off > 0; off >>= 1) {
            m0 = fmaxf(m0, __shfl_xor(m0, off, 64));
            m1 = fmaxf(m1, __shfl_xor(m1, off, 64));
        }
        float p00 = __expf(s00 - m0), p01 = __expf(s01 - m0), p02 = __expf(s02 - m0);
        float p10 = __expf(s10 - m1), p11 = __expf(s11 - m1), p12 = __expf(s12 - m1);
        float sum0 = p00 + p01 + p02, sum1 = p10 + p11 + p12;
        #pragma unroll
        for (int off = 32; off > 0; off >>= 1) {
            sum0 += __shfl_xor(sum0, off, 64);
            sum1 += __shfl_xor(sum1, off, 64);
        }
        ps[w][0][c0] = p00; ps[w][0][c1] = p01; ps[w][0][c2] = p02;
        ps[w][1][c0] = p10; ps[w][1][c1] = p11; ps[w][1][c2] = p12;
        asm volatile("" ::: "memory");

        float o0 = 0.f, o1 = 0.f;
        const ushort* vrow = &Vt[lane * CST];
        int c = 0;
        for (; c + 4 <= nc; c += 4) {
            float4 pv0 = *reinterpret_cast<const float4*>(&ps[w][0][c]);
            float4 pv1 = *reinterpret_cast<const float4*>(&ps[w][1][c]);
            unsigned va = *reinterpret_cast<const unsigned*>(&vrow[c]);
            unsigned vb2 = *reinterpret_cast<const unsigned*>(&vrow[c + 2]);
            float vf0 = __uint_as_float(va << 16);
            float vf1 = __uint_as_float(va & 0xFFFF0000u);
            float vf2 = __uint_as_float(vb2 << 16);
            float vf3 = __uint_as_float(vb2 & 0xFFFF0000u);
            o0 += pv0.x * vf0 + pv0.y * vf1 + pv0.z * vf2 + pv0.w * vf3;
            o1 += pv1.x * vf0 + pv1.y * vf1 + pv1.z * vf2 + pv1.w * vf3;
        }
        for (; c < nc; ++c) {
            float vf = bf2f(vrow[c]);
            o0 += ps[w][0][c] * vf;
            o1 += ps[w][1][c] * vf;
        }

        ushort hh, ll;
        split1(o0 / sum0, hh, ll);
        size_t ob0 = ((size_t)qrow0 * B + b) * D + h * 64 + lane;
        outH[ob0] = hh; outL[ob0] = ll;
        if (two) {
            split1(o1 / sum1, hh, ll);
            size_t ob1 = ((size_t)qrow1 * B + b) * D + h * 64 + lane;
            outH[ob1] = hh; outL[ob1] = ll;
        }
    }
}

// ---------------- residual add + mems clip ----------------
__global__ __launch_bounds__(256) void resid_clip(const float* __restrict__ obuf,
                                                  const float* __restrict__ rc,
                                                  const float* __restrict__ utt,
                                                  float* __restrict__ result,
                                                  float* __restrict__ out_mems) {
    size_t idx = (size_t)blockIdx.x * 256 + threadIdx.x;
    size_t f = idx * 4;
    if (f >= (size_t)Q * B * D) return;
    int row = (int)(f >> 10);
    float4 o = *reinterpret_cast<const float4*>(&obuf[f]);
    if (row < RT * B) {
        const float* res = (row < R * B) ? &rc[f] : &utt[f - (size_t)R * B * D];
        float4 rv = *reinterpret_cast<const float4*>(res);
        o.x += rv.x; o.y += rv.y; o.z += rv.z; o.w += rv.w;
        *reinterpret_cast<float4*>(&result[f]) = o;
    } else {
        o.x = fminf(fmaxf(o.x, -10.f), 10.f);
        o.y = fminf(fmaxf(o.y, -10.f), 10.f);
        o.z = fminf(fmaxf(o.z, -10.f), 10.f);
        o.w = fminf(fmaxf(o.w, -10.f), 10.f);
        *reinterpret_cast<float4*>(&out_mems[f - (size_t)RT * B * D]) = o;
    }
}

// ---------------- launch ----------------
extern "C" void kernel_launch(void* const* d_in, const int* in_sizes, int n_in,
                              void* d_out, int out_size, void* d_ws, size_t ws_size,
                              hipStream_t stream) {
    const float* utt   = (const float*)d_in[0];
    const float* rc    = (const float*)d_in[1];
    const float* mems  = (const float*)d_in[2];
    const float* lng   = (const float*)d_in[3];
    const float* lnb   = (const float*)d_in[4];
    const float* Wq    = (const float*)d_in[5];
    const float* bq    = (const float*)d_in[6];
    const float* Wkv   = (const float*)d_in[7];
    const float* bkv   = (const float*)d_in[8];
    const float* Wo    = (const float*)d_in[9];
    const float* bo    = (const float*)d_in[10];
    const float* ffg   = (const float*)d_in[11];
    const float* ffb   = (const float*)d_in[12];
    const float* W1    = (const float*)d_in[13];
    const float* b1    = (const float*)d_in[14];
    const float* W2    = (const float*)d_in[15];
    const float* b2    = (const float*)d_in[16];
    const float* outg  = (const float*)d_in[17];
    const float* outb  = (const float*)d_in[18];
    const int*   lens  = (const int*)d_in[19];

    constexpr int QBD  = Q * B * D;    // 4256 rows
    constexpr int KVBD = KV * B * D;   // 4254 rows

    float* ws = (float*)d_ws;
    size_t off = 0;
    auto allocF = [&](size_t n) { float* p = ws + off; off += (n + 63) & ~(size_t)63; return p; };
    auto allocU = [&](size_t n) { ushort* p = (ushort*)(ws + off); off += ((n + 1) / 2 + 63) & ~(size_t)63; return p; };

    float* f_q  = allocF(QBD);
    float* f_k  = allocF(KVBD);
    float* f_v  = allocF(KVBD);
    float* qxF  = allocF((size_t)RT * B * D);    // fp32 input-LN copy for summary
    ushort* qxH = allocU((size_t)MPAD * D);
    ushort* qxL = allocU((size_t)MPAD * D);
    ushort* kvH = allocU((size_t)MPAD * D);
    ushort* kvL = allocU((size_t)MPAD * D);
    ushort* atH = allocU((size_t)MPAD * D);
    ushort* atL = allocU((size_t)MPAD * D);
    ushort* flH = allocU((size_t)RT * B * D);
    ushort* flL = allocU((size_t)RT * B * D);
    ushort* fhH = allocU((size_t)RT * B * FFN);
    ushort* fhL = allocU((size_t)RT * B * FFN);
    ushort* wH  = allocU((size_t)FFN * D);
    ushort* wL  = allocU((size_t)FFN * D);
    // fp32 aliases — capacity-checked (r3/r4 bug: obuf=f_k had 4254 < 4256 rows):
    float* obuf   = f_q;   // Wo out: 4256 rows; f_q has 4256. attn consumed q first.
    float* result = f_v;   // 4224 rows; f_v has 4254. attn consumed v first.
    float* res2   = f_k;   // 4224 rows; f_k has 4254. attn consumed k first.
    float* out = (float*)d_out;

    auto wconv = [&](const float* src, int Mr, int Kd) {
        int kshift = (Kd == 1024) ? 8 : 10;
        int n4 = Mr * (Kd >> 2);
        split_bf16<<<(n4 + 255) / 256, 256, 0, stream>>>(src, wH, wL, Mr, kshift, n4);
    };
    auto gemm = [&](const ushort* ah, const ushort* al,
                    const float* bias, const float* resid, float* C,
                    ushort* CH, ushort* CL,
                    int Mr, int Mpad, int Nc, int Kd, float alpha, int relu) {
        dim3 g(Nc / 128, Mpad / 128);
        gemm_split<<<g, 256, 0, stream>>>(ah, al, wH, wL, bias, resid, C, CH, CL,
                                          Mr, Nc, Kd, alpha, relu);
    };

    // 0. zero bf16 pad rows (ws re-poisoned every call)
    zpad_kernel<<<96, 256, 0, stream>>>(qxH + (size_t)Q * B * D, qxL + (size_t)Q * B * D,
                                        (MPAD - Q * B) * D / 4);
    zpad_kernel<<<98, 256, 0, stream>>>(kvH + (size_t)KV * B * D, kvL + (size_t)KV * B * D,
                                        (MPAD - KV * B) * D / 4);
    zpad_kernel<<<96, 256, 0, stream>>>(atH + (size_t)Q * B * D, atL + (size_t)Q * B * D,
                                        (MPAD - Q * B) * D / 4);
    // 1. mems -> kvH/L rows [0, M*B)
    split_bf16<<<(M * B * 256 + 255) / 256, 256, 0, stream>>>(mems, kvH, kvL,
                                                              M * B, 8, M * B * 256);
    // 2. input LN -> qxF (fp32) + qxH/L rows [0,RT*B) + kvH/L rows [M*B, KV*B)
    ln2_kernel<<<RT * B, 256, 0, stream>>>(rc, utt, R * B, qxF, 0,
                                           qxH, qxL, kvH, kvL, M * B, lng, lnb);
    // 3. summary (fp32 source) -> qxH/L rows [RT*B, Q*B)
    summary3_kernel<<<N * B, 256, 0, stream>>>(qxF, qxH, qxL);
    // 4. q projection (scaled)
    wconv(Wq, D, D);
    gemm(qxH, qxL, bq, nullptr, f_q, nullptr, nullptr, Q * B, MPAD, D, D, 0.125f, 0);
    // 5/6. k and v projections
    wconv(Wkv, D, D);
    gemm(kvH, kvL, bkv, nullptr, f_k, nullptr, nullptr, KV * B, MPAD, D, D, 1.0f, 0);
    wconv(Wkv + (size_t)D * D, D, D);
    gemm(kvH, kvL, bkv + D, nullptr, f_v, nullptr, nullptr, KV * B, MPAD, D, D, 1.0f, 0);
    // 7. sparse attention -> atH/L (bf16 split, direct)
    attn2<<<N * B * H * 2, 256, 0, stream>>>(f_q, f_k, f_v, lens, atH, atL);
    // 8. output projection -> obuf (= f_q; q already consumed)
    wconv(Wo, D, D);
    gemm(atH, atL, bo, nullptr, obuf, nullptr, nullptr, Q * B, MPAD, D, D, 1.0f, 0);
    // 9. residual + mems clip
    resid_clip<<<(Q * B * D / 4 + 255) / 256, 256, 0, stream>>>(
        obuf, rc, utt, result, out + (size_t)(T + R) * B * D);
    // 10. FFN input LN -> flH/L (bf16 only)
    ln2_kernel<<<RT * B, 256, 0, stream>>>(result, result, RT * B, nullptr, 0,
                                           flH, flL, nullptr, nullptr, 0, ffg, ffb);
    // 11. FFN up + relu -> fhH/L (bf16 split epilogue)
    wconv(W1, FFN, D);
    gemm(flH, flL, b1, nullptr, nullptr, fhH, fhL, RT * B, RT * B, FFN, D, 1.0f, 1);
    // 12. FFN down + residual -> res2 (= f_k; k already consumed)
    wconv(W2, D, FFN);
    gemm(fhH, fhL, b2, result, res2, nullptr, nullptr, RT * B, RT * B, D, FFN, 1.0f, 0);
    // 13. output LN with row remap -> out
    ln2_kernel<<<RT * B, 256, 0, stream>>>(res2, res2, RT * B, out, 1,
                                           nullptr, nullptr, nullptr, nullptr, 0,
                                           outg, outb);
}

// Round 6
// 654.603 us; speedup vs baseline: 3.9390x; 1.4278x over previous
//
#include <hip/hip_runtime.h>

// ---------------- problem constants ----------------
constexpr int D   = 1024;
constexpr int H   = 16;
constexpr int FFN = 4096;
constexpr int SEG = 128;
constexpr int L   = 32;
constexpr int RCL = 4;
constexpr int T   = 2048;
constexpr int B   = 2;
constexpr int N   = T / SEG;   // 16
constexpr int M   = N - 1;     // 15
constexpr int R   = RCL * N;   // 64
constexpr int Q   = R + T + N; // 2128
constexpr int KV  = M + R + T; // 2127
constexpr int RT  = R + T;     // 2112
constexpr float EPS = 1e-5f;
constexpr int MPAD = 4352;     // ceil(4256/128)*128

typedef float f32x4 __attribute__((ext_vector_type(4)));
typedef __bf16 bf16x8 __attribute__((ext_vector_type(8)));
typedef short s16x4 __attribute__((ext_vector_type(4)));

// ---------------- helpers ----------------
__device__ __forceinline__ ushort bf16rne(float x) {
    unsigned u = __float_as_uint(x);
    return (ushort)((u + 0x7FFFu + ((u >> 16) & 1u)) >> 16);
}
__device__ __forceinline__ float bf2f(ushort h) {
    return __uint_as_float(((unsigned)h) << 16);
}

__device__ inline void block_reduce_2(float& s1, float& s2) {
    #pragma unroll
    for (int off = 32; off > 0; off >>= 1) {
        s1 += __shfl_xor(s1, off, 64);
        s2 += __shfl_xor(s2, off, 64);
    }
    __shared__ float red[8];
    int lane = threadIdx.x & 63, w = threadIdx.x >> 6;
    if (lane == 0) { red[w * 2] = s1; red[w * 2 + 1] = s2; }
    __syncthreads();
    s1 = red[0] + red[2] + red[4] + red[6];
    s2 = red[1] + red[3] + red[5] + red[7];
}

// async global->LDS, 16B per lane; lds base must be wave-uniform
__device__ __forceinline__ void gload16(const void* g, void* l) {
    __builtin_amdgcn_global_load_lds(
        (__attribute__((address_space(1))) void*)(uintptr_t)g,
        (__attribute__((address_space(3))) void*)(unsigned)(uintptr_t)l,
        16, 0, 0);
}

// ---------------- zero-pad bf16 pad rows ----------------
__global__ __launch_bounds__(256) void zpad_kernel(ushort* __restrict__ Bp, int n4) {
    int idx = blockIdx.x * 256 + threadIdx.x;
    if (idx < n4) {
        s16x4 z = {0, 0, 0, 0};
        *reinterpret_cast<s16x4*>(&Bp[(size_t)idx * 4]) = z;
    }
}

// ---------------- LayerNorm with fused bf16 output ----------------
// src row = row < split ? src0[row] : src1[row-split]
// dstF optional fp32 (remap applies the final-output row remap); B0/B1 optional bf16
__global__ __launch_bounds__(256) void ln2_kernel(const float* __restrict__ src0,
                                                  const float* __restrict__ src1,
                                                  int split,
                                                  float* __restrict__ dstF, int remap,
                                                  ushort* __restrict__ B0,
                                                  ushort* __restrict__ B1,
                                                  int rowoff1,
                                                  const float* __restrict__ gamma,
                                                  const float* __restrict__ beta) {
    int row = blockIdx.x;
    int t = threadIdx.x;
    const float* src = (row < split) ? src0 + (size_t)row * D
                                     : src1 + (size_t)(row - split) * D;
    float4 x = *reinterpret_cast<const float4*>(&src[t * 4]);
    float s1 = x.x + x.y + x.z + x.w;
    float s2 = x.x * x.x + x.y * x.y + x.z * x.z + x.w * x.w;
    block_reduce_2(s1, s2);
    float mean = s1 * (1.0f / D);
    float var  = s2 * (1.0f / D) - mean * mean;
    float rs = rsqrtf(var + EPS);
    float4 g4 = *reinterpret_cast<const float4*>(&gamma[t * 4]);
    float4 b4 = *reinterpret_cast<const float4*>(&beta[t * 4]);
    float y[4];
    y[0] = (x.x - mean) * rs * g4.x + b4.x;
    y[1] = (x.y - mean) * rs * g4.y + b4.y;
    y[2] = (x.z - mean) * rs * g4.z + b4.z;
    y[3] = (x.w - mean) * rs * g4.w + b4.w;
    if (dstF) {
        size_t off;
        if (!remap) off = (size_t)row * D;
        else off = (row < R * B) ? ((size_t)T * B * D + (size_t)row * D)
                                 : ((size_t)(row - R * B) * D);
        *reinterpret_cast<float4*>(&dstF[off + t * 4]) =
            make_float4(y[0], y[1], y[2], y[3]);
    }
    if (B0) {
        s16x4 h4;
        #pragma unroll
        for (int j = 0; j < 4; ++j) h4[j] = (short)bf16rne(y[j]);
        size_t o0 = (size_t)row * D + t * 4;
        *reinterpret_cast<s16x4*>(&B0[o0]) = h4;
        if (B1) {
            size_t o1 = (size_t)(row + rowoff1) * D + t * 4;
            *reinterpret_cast<s16x4*>(&B1[o1]) = h4;
        }
    }
}

// ---------------- summary (mean over SEG rows, fp32 source) -> bf16 ----------
__global__ __launch_bounds__(256) void summary3_kernel(const float* __restrict__ qxF,
                                                       ushort* __restrict__ qxB) {
    int nb = blockIdx.x;          // N*B = 32
    int n = nb >> 1, b = nb & 1;
    int t = threadIdx.x;
    float acc[4] = {0.f, 0.f, 0.f, 0.f};
    for (int s = 0; s < SEG; ++s) {
        size_t base = ((size_t)((R + n * SEG + s) * B + b)) * D + t * 4;
        float4 x = *reinterpret_cast<const float4*>(&qxF[base]);
        acc[0] += x.x; acc[1] += x.y; acc[2] += x.z; acc[3] += x.w;
    }
    s16x4 h4;
    #pragma unroll
    for (int j = 0; j < 4; ++j) h4[j] = (short)bf16rne(acc[j] * (1.0f / SEG));
    size_t dst = ((size_t)(RT * B + nb)) * D + t * 4;
    *reinterpret_cast<s16x4*>(&qxB[dst]) = h4;
}

// ---------------- fp32 -> bf16 convert (weights + mems), zero-pads tail ------
__global__ __launch_bounds__(256) void cvt_bf16(const float* __restrict__ src,
                                                ushort* __restrict__ dst,
                                                int Mr, int kshift, int n4) {
    int idx = blockIdx.x * 256 + threadIdx.x;
    if (idx >= n4) return;
    int row = idx >> kshift;
    size_t e = (size_t)idx * 4;
    s16x4 h = {0, 0, 0, 0};
    if (row < Mr) {
        float4 x = *reinterpret_cast<const float4*>(&src[e]);
        h[0] = (short)bf16rne(x.x);
        h[1] = (short)bf16rne(x.y);
        h[2] = (short)bf16rne(x.z);
        h[3] = (short)bf16rne(x.w);
    }
    *reinterpret_cast<s16x4*>(&dst[e]) = h;
}

// ---------------- bf16 MFMA GEMM (m97 structure, 128x128, BK=32) --------------
// C[m][n] = (sum_k A[m][k]*W[n][k] + bias[n]) * alpha  (+relu) (+residual)
// 1D grid with bijective XCD-chunk swizzle (T1/m204): each XCD owns a
// contiguous run of row-panels -> A-panel fetched ~once per XCD.
__global__ __launch_bounds__(256) void gemm_bf(const ushort* __restrict__ A,
                                               const ushort* __restrict__ W,
                                               const float* __restrict__ bias,
                                               const float* __restrict__ residual,
                                               float* __restrict__ C,
                                               ushort* __restrict__ CB,
                                               int Mr, int Nc, int Kd,
                                               float alpha, int do_relu, int gx) {
    __shared__ __align__(16) ushort sm[2 * 4096];   // A | W (16 KB)
    ushort* sA = sm;
    ushort* sW = sm + 4096;

    // XCD-chunk swizzle (bijective for any nwg)
    int bid = blockIdx.x;
    int nwg = gridDim.x;
    int q8 = nwg >> 3, r8 = nwg & 7;
    int c8 = bid & 7, j8 = bid >> 3;
    int lin = (c8 < r8 ? c8 * (q8 + 1) : r8 * (q8 + 1) + (c8 - r8) * q8) + j8;
    const int bn0 = (lin % gx) * 128;
    const int bm0 = (lin / gx) * 128;

    const int t = threadIdx.x;
    const int w = t >> 6, lane = t & 63;
    const int wr = w >> 1, wc = w & 1;
    const int fr = lane & 15, fq = lane >> 4;

    const int srow = lane >> 2;
    const int scol = (lane & 3) * 8;
    const size_t aR0 = (size_t)(bm0 + w * 32 + srow) * Kd + scol;
    const size_t aR1 = aR0 + (size_t)16 * Kd;
    const size_t wR0 = (size_t)(bn0 + w * 32 + srow) * Kd + scol;
    const size_t wR1 = wR0 + (size_t)16 * Kd;
    const int lbase = w * 1024;

    f32x4 acc[4][4];
    #pragma unroll
    for (int m = 0; m < 4; ++m)
        #pragma unroll
        for (int n = 0; n < 4; ++n) acc[m][n] = f32x4{0.f, 0.f, 0.f, 0.f};

    const int ao = (wr * 64 + fr) * 32 + fq * 8;
    const int wo = (wc * 64 + fr) * 32 + fq * 8;

    for (int k0 = 0; k0 < Kd; k0 += 32) {
        gload16(A + aR0 + k0, sA + lbase);
        gload16(A + aR1 + k0, sA + lbase + 512);
        gload16(W + wR0 + k0, sW + lbase);
        gload16(W + wR1 + k0, sW + lbase + 512);
        __syncthreads();   // compiler drains vmcnt before barrier

        bf16x8 bh[4];
        #pragma unroll
        for (int n = 0; n < 4; ++n)
            bh[n] = *reinterpret_cast<const bf16x8*>(&sW[wo + n * 512]);
        #pragma unroll
        for (int m = 0; m < 4; ++m) {
            bf16x8 ah = *reinterpret_cast<const bf16x8*>(&sA[ao + m * 512]);
            #pragma unroll
            for (int n = 0; n < 4; ++n)
                acc[m][n] = __builtin_amdgcn_mfma_f32_16x16x32_bf16(ah, bh[n], acc[m][n], 0, 0, 0);
        }
        __syncthreads();
    }

    // epilogue: C/D layout col=lane&15, row=(lane>>4)*4+j  [m89-verified]
    float bv[4];
    #pragma unroll
    for (int n = 0; n < 4; ++n) bv[n] = bias[bn0 + wc * 64 + n * 16 + fr];
    #pragma unroll
    for (int m = 0; m < 4; ++m) {
        #pragma unroll
        for (int j = 0; j < 4; ++j) {
            int row = bm0 + wr * 64 + m * 16 + fq * 4 + j;
            if (row < Mr) {
                #pragma unroll
                for (int n = 0; n < 4; ++n) {
                    int col = bn0 + wc * 64 + n * 16 + fr;
                    float v = (acc[m][n][j] + bv[n]) * alpha;
                    if (do_relu) v = fmaxf(v, 0.f);
                    if (residual) v += residual[(size_t)row * Nc + col];
                    if (CB) CB[(size_t)row * Nc + col] = bf16rne(v);
                    else    C[(size_t)row * Nc + col] = v;
                }
            }
        }
    }
}

// ---------------- sparse masked attention (r5-validated body, bf16 out) ------
// 1024 blocks = (b,h,i,half). K fp32 in LDS [64][KTS]; V bf16 in LDS [64][CST];
// 2 q-rows per wave-iteration.
constexpr int KTS = 181;   // fp32 K stride (odd -> conflict-free lane-per-col)
constexpr int CST = 186;   // bf16 V stride
constexpr int CMX = 192;

__global__ __launch_bounds__(256) void attn2(const float* __restrict__ qb,
                                             const float* __restrict__ kb,
                                             const float* __restrict__ vb,
                                             const int* __restrict__ lengths,
                                             ushort* __restrict__ outB) {
    __shared__ __align__(16) float  Kt[64 * KTS];
    __shared__ __align__(16) ushort Vt[64 * CST];
    __shared__ __align__(16) float  ps[4][2][CMX];
    __shared__ __align__(16) float  qs[4][2][64];
    __shared__ int colmap[CMX];

    int gid = blockIdx.x;
    int half = gid & 1;
    int i = (gid >> 1) & 15;
    int h = (gid >> 5) & 15;
    int b = gid >> 9;
    int t = threadIdx.x;
    int lane = t & 63, w = t >> 6;

    int nm = i;
    int u0 = (i * SEG - L > 0) ? (i * SEG - L) : 0;
    int nc = nm + RCL + (i + 1) * SEG - u0;

    int maxlen = max(lengths[0], lengths[1]);
    int kl = lengths[b] + (M + R + T) - maxlen;

    for (int c = t; c < nc; c += 256) {
        int g;
        if (c < nm)            g = c;
        else if (c < nm + RCL) g = M + i * RCL + (c - nm);
        else                   g = M + R + u0 + (c - nm - RCL);
        colmap[c] = g;
    }
    __syncthreads();

    for (int f = t; f < nc * 16; f += 256) {
        int c = f >> 4, dc = f & 15;
        int g = colmap[c];
        size_t base = ((size_t)g * B + b) * D + h * 64 + dc * 4;
        float4 k4 = *reinterpret_cast<const float4*>(&kb[base]);
        Kt[(dc * 4 + 0) * KTS + c] = k4.x;
        Kt[(dc * 4 + 1) * KTS + c] = k4.y;
        Kt[(dc * 4 + 2) * KTS + c] = k4.z;
        Kt[(dc * 4 + 3) * KTS + c] = k4.w;
        float4 v4 = *reinterpret_cast<const float4*>(&vb[base]);
        Vt[(dc * 4 + 0) * CST + c] = bf16rne(v4.x);
        Vt[(dc * 4 + 1) * CST + c] = bf16rne(v4.y);
        Vt[(dc * 4 + 2) * CST + c] = bf16rne(v4.z);
        Vt[(dc * 4 + 3) * CST + c] = bf16rne(v4.w);
    }
    __syncthreads();

    const int nrows = half ? 65 : 68;
    const int rbase = half ? 68 : 0;
    const int c0 = lane, c1 = lane + 64, c2 = lane + 128;
    bool v0 = (c0 < nc) && (colmap[c0] < kl);
    bool v1 = (c1 < nc) && (colmap[c1] < kl);
    bool v2 = (c2 < nc) && (colmap[c2] < kl);

    for (int rl = w * 2; rl < nrows; rl += 8) {
        int r0 = rbase + rl;
        bool two = (rl + 1 < nrows);
        int r1 = two ? r0 + 1 : r0;
        int qrow0 = (r0 < RCL) ? i * RCL + r0
                  : (r0 < 132) ? R + i * SEG + (r0 - RCL)
                               : R + T + i;
        int qrow1 = (r1 < RCL) ? i * RCL + r1
                  : (r1 < 132) ? R + i * SEG + (r1 - RCL)
                               : R + T + i;

        qs[w][0][lane] = qb[((size_t)qrow0 * B + b) * D + h * 64 + lane];
        qs[w][1][lane] = qb[((size_t)qrow1 * B + b) * D + h * 64 + lane];
        asm volatile("" ::: "memory");

        float a00 = 0.f, a01 = 0.f, a02 = 0.f;
        float a10 = 0.f, a11 = 0.f, a12 = 0.f;
        #pragma unroll
        for (int d = 0; d < 64; d += 4) {
            float4 q0 = *reinterpret_cast<const float4*>(&qs[w][0][d]);
            float4 q1 = *reinterpret_cast<const float4*>(&qs[w][1][d]);
            #pragma unroll
            for (int dd = 0; dd < 4; ++dd) {
                float k0 = Kt[(d + dd) * KTS + c0];
                float k1 = Kt[(d + dd) * KTS + c1];
                float k2 = Kt[(d + dd) * KTS + c2];
                float qa = (dd == 0) ? q0.x : (dd == 1) ? q0.y : (dd == 2) ? q0.z : q0.w;
                float qbv = (dd == 0) ? q1.x : (dd == 1) ? q1.y : (dd == 2) ? q1.z : q1.w;
                a00 += qa * k0;  a01 += qa * k1;  a02 += qa * k2;
                a10 += qbv * k0; a11 += qbv * k1; a12 += qbv * k2;
            }
        }
        float s00 = v0 ? a00 : -1e30f, s01 = v1 ? a01 : -1e30f, s02 = v2 ? a02 : -1e30f;
        float s10 = v0 ? a10 : -1e30f, s11 = v1 ? a11 : -1e30f, s12 = v2 ? a12 : -1e30f;

        float m0 = fmaxf(fmaxf(s00, s01), s02);
        float m1 = fmaxf(fmaxf(s10, s11), s12);
        #pragma unroll
        for (int off = 32; off > 0; off >>= 1) {
            m0 = fmaxf(m0, __shfl_xor(m0, off, 64));
            m1 = fmaxf(m1, __shfl_xor(m1, off, 64));
        }
        float p00 = __expf(s00 - m0), p01 = __expf(s01 - m0), p02 = __expf(s02 - m0);
        float p10 = __expf(s10 - m1), p11 = __expf(s11 - m1), p12 = __expf(s12 - m1);
        float sum0 = p00 + p01 + p02, sum1 = p10 + p11 + p12;
        #pragma unroll
        for (int off = 32; off > 0; off >>= 1) {
            sum0 += __shfl_xor(sum0, off, 64);
            sum1 += __shfl_xor(sum1, off, 64);
        }
        ps[w][0][c0] = p00; ps[w][0][c1] = p01; ps[w][0][c2] = p02;
        ps[w][1][c0] = p10; ps[w][1][c1] = p11; ps[w][1][c2] = p12;
        asm volatile("" ::: "memory");

        float o0 = 0.f, o1 = 0.f;
        const ushort* vrow = &Vt[lane * CST];
        int c = 0;
        for (; c + 4 <= nc; c += 4) {
            float4 pv0 = *reinterpret_cast<const float4*>(&ps[w][0][c]);
            float4 pv1 = *reinterpret_cast<const float4*>(&ps[w][1][c]);
            unsigned va = *reinterpret_cast<const unsigned*>(&vrow[c]);
            unsigned vb2 = *reinterpret_cast<const unsigned*>(&vrow[c + 2]);
            float vf0 = __uint_as_float(va << 16);
            float vf1 = __uint_as_float(va & 0xFFFF0000u);
            float vf2 = __uint_as_float(vb2 << 16);
            float vf3 = __uint_as_float(vb2 & 0xFFFF0000u);
            o0 += pv0.x * vf0 + pv0.y * vf1 + pv0.z * vf2 + pv0.w * vf3;
            o1 += pv1.x * vf0 + pv1.y * vf1 + pv1.z * vf2 + pv1.w * vf3;
        }
        for (; c < nc; ++c) {
            float vf = bf2f(vrow[c]);
            o0 += ps[w][0][c] * vf;
            o1 += ps[w][1][c] * vf;
        }

        size_t ob0 = ((size_t)qrow0 * B + b) * D + h * 64 + lane;
        outB[ob0] = bf16rne(o0 / sum0);
        if (two) {
            size_t ob1 = ((size_t)qrow1 * B + b) * D + h * 64 + lane;
            outB[ob1] = bf16rne(o1 / sum1);
        }
    }
}

// ---------------- residual add + mems clip ----------------
__global__ __launch_bounds__(256) void resid_clip(const float* __restrict__ obuf,
                                                  const float* __restrict__ rc,
                                                  const float* __restrict__ utt,
                                                  float* __restrict__ result,
                                                  float* __restrict__ out_mems) {
    size_t idx = (size_t)blockIdx.x * 256 + threadIdx.x;
    size_t f = idx * 4;
    if (f >= (size_t)Q * B * D) return;
    int row = (int)(f >> 10);
    float4 o = *reinterpret_cast<const float4*>(&obuf[f]);
    if (row < RT * B) {
        const float* res = (row < R * B) ? &rc[f] : &utt[f - (size_t)R * B * D];
        float4 rv = *reinterpret_cast<const float4*>(res);
        o.x += rv.x; o.y += rv.y; o.z += rv.z; o.w += rv.w;
        *reinterpret_cast<float4*>(&result[f]) = o;
    } else {
        o.x = fminf(fmaxf(o.x, -10.f), 10.f);
        o.y = fminf(fmaxf(o.y, -10.f), 10.f);
        o.z = fminf(fmaxf(o.z, -10.f), 10.f);
        o.w = fminf(fmaxf(o.w, -10.f), 10.f);
        *reinterpret_cast<float4*>(&out_mems[f - (size_t)RT * B * D]) = o;
    }
}

// ---------------- launch ----------------
extern "C" void kernel_launch(void* const* d_in, const int* in_sizes, int n_in,
                              void* d_out, int out_size, void* d_ws, size_t ws_size,
                              hipStream_t stream) {
    const float* utt   = (const float*)d_in[0];
    const float* rc    = (const float*)d_in[1];
    const float* mems  = (const float*)d_in[2];
    const float* lng   = (const float*)d_in[3];
    const float* lnb   = (const float*)d_in[4];
    const float* Wq    = (const float*)d_in[5];
    const float* bq    = (const float*)d_in[6];
    const float* Wkv   = (const float*)d_in[7];
    const float* bkv   = (const float*)d_in[8];
    const float* Wo    = (const float*)d_in[9];
    const float* bo    = (const float*)d_in[10];
    const float* ffg   = (const float*)d_in[11];
    const float* ffb   = (const float*)d_in[12];
    const float* W1    = (const float*)d_in[13];
    const float* b1    = (const float*)d_in[14];
    const float* W2    = (const float*)d_in[15];
    const float* b2    = (const float*)d_in[16];
    const float* outg  = (const float*)d_in[17];
    const float* outb  = (const float*)d_in[18];
    const int*   lens  = (const int*)d_in[19];

    constexpr int QBD  = Q * B * D;    // 4256 rows
    constexpr int KVBD = KV * B * D;   // 4254 rows

    float* ws = (float*)d_ws;
    size_t off = 0;
    auto allocF = [&](size_t n) { float* p = ws + off; off += (n + 63) & ~(size_t)63; return p; };
    auto allocU = [&](size_t n) { ushort* p = (ushort*)(ws + off); off += ((n + 1) / 2 + 63) & ~(size_t)63; return p; };

    float* f_q  = allocF(QBD);
    float* f_k  = allocF(KVBD);
    float* f_v  = allocF(KVBD);
    float* qxF  = allocF((size_t)RT * B * D);    // fp32 input-LN copy for summary
    ushort* qxB = allocU((size_t)MPAD * D);
    ushort* kvB = allocU((size_t)MPAD * D);
    ushort* atB = allocU((size_t)MPAD * D);
    ushort* flB = allocU((size_t)RT * B * D);
    ushort* fhB = allocU((size_t)RT * B * FFN);
    ushort* wB  = allocU((size_t)FFN * D);
    // fp32 aliases — capacity-checked (r3/r4 lesson: check ROW capacity!):
    float* obuf   = f_q;   // Wo out: 4256 rows; f_q has 4256. attn consumed q first.
    float* result = f_v;   // 4224 rows; f_v has 4254. attn consumed v first.
    float* res2   = f_k;   // 4224 rows; f_k has 4254. attn consumed k first.
    float* out = (float*)d_out;

    auto wconv = [&](const float* src, int Mr, int Kd) {
        int kshift = (Kd == 1024) ? 8 : 10;
        int n4 = Mr * (Kd >> 2);
        cvt_bf16<<<(n4 + 255) / 256, 256, 0, stream>>>(src, wB, Mr, kshift, n4);
    };
    auto gemm = [&](const ushort* a, const float* bias, const float* resid,
                    float* C, ushort* CB,
                    int Mr, int Mpad, int Nc, int Kd, float alpha, int relu) {
        int gx = Nc / 128, gy = Mpad / 128;
        gemm_bf<<<gx * gy, 256, 0, stream>>>(a, wB, bias, resid, C, CB,
                                             Mr, Nc, Kd, alpha, relu, gx);
    };

    // 0. zero bf16 pad rows (ws re-poisoned every call)
    zpad_kernel<<<96, 256, 0, stream>>>(qxB + (size_t)Q * B * D, (MPAD - Q * B) * D / 4);
    zpad_kernel<<<98, 256, 0, stream>>>(kvB + (size_t)KV * B * D, (MPAD - KV * B) * D / 4);
    zpad_kernel<<<96, 256, 0, stream>>>(atB + (size_t)Q * B * D, (MPAD - Q * B) * D / 4);
    // 1. mems -> kvB rows [0, M*B)
    cvt_bf16<<<(M * B * 256 + 255) / 256, 256, 0, stream>>>(mems, kvB, M * B, 8,
                                                            M * B * 256);
    // 2. input LN -> qxF (fp32) + qxB rows [0,RT*B) + kvB rows [M*B, KV*B)
    ln2_kernel<<<RT * B, 256, 0, stream>>>(rc, utt, R * B, qxF, 0,
                                           qxB, kvB, M * B, lng, lnb);
    // 3. summary (fp32 source) -> qxB rows [RT*B, Q*B)
    summary3_kernel<<<N * B, 256, 0, stream>>>(qxF, qxB);
    // 4. q projection (scaled)
    wconv(Wq, D, D);
    gemm(qxB, bq, nullptr, f_q, nullptr, Q * B, MPAD, D, D, 0.125f, 0);
    // 5/6. k and v projections
    wconv(Wkv, D, D);
    gemm(kvB, bkv, nullptr, f_k, nullptr, KV * B, MPAD, D, D, 1.0f, 0);
    wconv(Wkv + (size_t)D * D, D, D);
    gemm(kvB, bkv + D, nullptr, f_v, nullptr, KV * B, MPAD, D, D, 1.0f, 0);
    // 7. sparse attention -> atB (bf16, direct)
    attn2<<<N * B * H * 2, 256, 0, stream>>>(f_q, f_k, f_v, lens, atB);
    // 8. output projection -> obuf (= f_q; q already consumed)
    wconv(Wo, D, D);
    gemm(atB, bo, nullptr, obuf, nullptr, Q * B, MPAD, D, D, 1.0f, 0);
    // 9. residual + mems clip
    resid_clip<<<(Q * B * D / 4 + 255) / 256, 256, 0, stream>>>(
        obuf, rc, utt, result, out + (size_t)(T + R) * B * D);
    // 10. FFN input LN -> flB
    ln2_kernel<<<RT * B, 256, 0, stream>>>(result, result, RT * B, nullptr, 0,
                                           flB, nullptr, 0, ffg, ffb);
    // 11. FFN up + relu -> fhB (bf16 epilogue)
    wconv(W1, FFN, D);
    gemm(flB, b1, nullptr, nullptr, fhB, RT * B, RT * B, FFN, D, 1.0f, 1);
    // 12. FFN down + residual -> res2 (= f_k; k already consumed)
    wconv(W2, D, FFN);
    gemm(fhB, b2, result, res2, nullptr, RT * B, RT * B, D, FFN, 1.0f, 0);
    // 13. output LN with row remap -> out
    ln2_kernel<<<RT * B, 256, 0, stream>>>(res2, res2, RT * B, out, 1,
                                           nullptr, nullptr, 0, outg, outb);
}

// Round 7
// 584.037 us; speedup vs baseline: 4.4149x; 1.1208x over previous
//
#include <hip/hip_runtime.h>

// ---------------- problem constants ----------------
constexpr int D   = 1024;
constexpr int H   = 16;
constexpr int FFN = 4096;
constexpr int SEG = 128;
constexpr int L   = 32;
constexpr int RCL = 4;
constexpr int T   = 2048;
constexpr int B   = 2;
constexpr int N   = T / SEG;   // 16
constexpr int M   = N - 1;     // 15
constexpr int R   = RCL * N;   // 64
constexpr int Q   = R + T + N; // 2128
constexpr int KV  = M + R + T; // 2127
constexpr int RT  = R + T;     // 2112
constexpr float EPS = 1e-5f;
constexpr int MPAD = 4352;     // ceil(4256/128)*128
constexpr int KVSTR = 2048;    // fused k|v projection row stride

typedef float f32x4 __attribute__((ext_vector_type(4)));
typedef __bf16 bf16x8 __attribute__((ext_vector_type(8)));
typedef short s16x4 __attribute__((ext_vector_type(4)));
typedef unsigned u32x4 __attribute__((ext_vector_type(4)));
typedef ushort us4 __attribute__((ext_vector_type(4)));
typedef _Float16 h2_t __attribute__((ext_vector_type(2)));

// ---------------- helpers ----------------
__device__ __forceinline__ ushort bf16rne(float x) {
    unsigned u = __float_as_uint(x);
    return (ushort)((u + 0x7FFFu + ((u >> 16) & 1u)) >> 16);
}
__device__ __forceinline__ ushort f2h(float x) {
    _Float16 h = (_Float16)x;
    ushort u; __builtin_memcpy(&u, &h, 2); return u;
}
__device__ __forceinline__ h2_t uh2(unsigned u) {
    h2_t h; __builtin_memcpy(&h, &u, 4); return h;
}
#define FDOT2(a, b, c) __builtin_amdgcn_fdot2((a), (b), (c), false)

__device__ inline void block_reduce_2(float& s1, float& s2) {
    #pragma unroll
    for (int off = 32; off > 0; off >>= 1) {
        s1 += __shfl_xor(s1, off, 64);
        s2 += __shfl_xor(s2, off, 64);
    }
    __shared__ float red[8];
    int lane = threadIdx.x & 63, w = threadIdx.x >> 6;
    if (lane == 0) { red[w * 2] = s1; red[w * 2 + 1] = s2; }
    __syncthreads();
    s1 = red[0] + red[2] + red[4] + red[6];
    s2 = red[1] + red[3] + red[5] + red[7];
}

// async global->LDS, 16B per lane; lds base must be wave-uniform
__device__ __forceinline__ void gload16(const void* g, void* l) {
    __builtin_amdgcn_global_load_lds(
        (__attribute__((address_space(1))) void*)(uintptr_t)g,
        (__attribute__((address_space(3))) void*)(unsigned)(uintptr_t)l,
        16, 0, 0);
}

// ---------------- prep: all weight/mems bf16 converts + pad zeroing, 1 kernel --
__global__ __launch_bounds__(256) void prep_kernel(const float* __restrict__ Wq,
                                                   const float* __restrict__ Wkv,
                                                   const float* __restrict__ Wo,
                                                   const float* __restrict__ W1,
                                                   const float* __restrict__ W2,
                                                   const float* __restrict__ mems,
                                                   ushort* __restrict__ wAll,
                                                   ushort* __restrict__ kvB,
                                                   ushort* __restrict__ qxB,
                                                   ushort* __restrict__ atB) {
    int idx = blockIdx.x * 256 + threadIdx.x;
    constexpr int n0 = D * D / 4;                 // Wq
    constexpr int n1 = n0 + 2 * D * D / 4;        // Wkv
    constexpr int n2 = n1 + D * D / 4;            // Wo
    constexpr int n3 = n2 + FFN * D / 4;          // W1
    constexpr int n4 = n3 + FFN * D / 4;          // W2
    constexpr int n5 = n4 + M * B * D / 4;        // mems -> kvB rows [0, M*B)
    constexpr int n6 = n5 + (MPAD - Q * B) * D / 4;   // qxB pad
    constexpr int n7 = n6 + (MPAD - KV * B) * D / 4;  // kvB pad
    constexpr int n8 = n7 + (MPAD - Q * B) * D / 4;   // atB pad
    if (idx >= n8) return;
    const float* src = nullptr; ushort* dst; int rel;
    if (idx < n0)      { src = Wq;   dst = wAll;                              rel = idx; }
    else if (idx < n1) { src = Wkv;  dst = wAll + D * D;                      rel = idx - n0; }
    else if (idx < n2) { src = Wo;   dst = wAll + 3 * D * D;                  rel = idx - n1; }
    else if (idx < n3) { src = W1;   dst = wAll + 4 * D * D;                  rel = idx - n2; }
    else if (idx < n4) { src = W2;   dst = wAll + 4 * D * D + FFN * D;        rel = idx - n3; }
    else if (idx < n5) { src = mems; dst = kvB;                               rel = idx - n4; }
    else if (idx < n6) { dst = qxB + (size_t)Q * B * D;                       rel = idx - n5; }
    else if (idx < n7) { dst = kvB + (size_t)KV * B * D;                      rel = idx - n6; }
    else               { dst = atB + (size_t)Q * B * D;                       rel = idx - n7; }
    s16x4 hv = {0, 0, 0, 0};
    if (src) {
        float4 x = *reinterpret_cast<const float4*>(&src[(size_t)rel * 4]);
        hv[0] = (short)bf16rne(x.x); hv[1] = (short)bf16rne(x.y);
        hv[2] = (short)bf16rne(x.z); hv[3] = (short)bf16rne(x.w);
    }
    *reinterpret_cast<s16x4*>(&dst[(size_t)rel * 4]) = hv;
}

// ---------------- LayerNorm with fused bf16 output ----------------
__global__ __launch_bounds__(256) void ln2_kernel(const float* __restrict__ src0,
                                                  const float* __restrict__ src1,
                                                  int split,
                                                  float* __restrict__ dstF, int remap,
                                                  ushort* __restrict__ B0,
                                                  ushort* __restrict__ B1,
                                                  int rowoff1,
                                                  const float* __restrict__ gamma,
                                                  const float* __restrict__ beta) {
    int row = blockIdx.x;
    int t = threadIdx.x;
    const float* src = (row < split) ? src0 + (size_t)row * D
                                     : src1 + (size_t)(row - split) * D;
    float4 x = *reinterpret_cast<const float4*>(&src[t * 4]);
    float s1 = x.x + x.y + x.z + x.w;
    float s2 = x.x * x.x + x.y * x.y + x.z * x.z + x.w * x.w;
    block_reduce_2(s1, s2);
    float mean = s1 * (1.0f / D);
    float var  = s2 * (1.0f / D) - mean * mean;
    float rs = rsqrtf(var + EPS);
    float4 g4 = *reinterpret_cast<const float4*>(&gamma[t * 4]);
    float4 b4 = *reinterpret_cast<const float4*>(&beta[t * 4]);
    float y[4];
    y[0] = (x.x - mean) * rs * g4.x + b4.x;
    y[1] = (x.y - mean) * rs * g4.y + b4.y;
    y[2] = (x.z - mean) * rs * g4.z + b4.z;
    y[3] = (x.w - mean) * rs * g4.w + b4.w;
    if (dstF) {
        size_t off;
        if (!remap) off = (size_t)row * D;
        else off = (row < R * B) ? ((size_t)T * B * D + (size_t)row * D)
                                 : ((size_t)(row - R * B) * D);
        *reinterpret_cast<float4*>(&dstF[off + t * 4]) =
            make_float4(y[0], y[1], y[2], y[3]);
    }
    if (B0) {
        s16x4 h4;
        #pragma unroll
        for (int j = 0; j < 4; ++j) h4[j] = (short)bf16rne(y[j]);
        size_t o0 = (size_t)row * D + t * 4;
        *reinterpret_cast<s16x4*>(&B0[o0]) = h4;
        if (B1) {
            size_t o1 = (size_t)(row + rowoff1) * D + t * 4;
            *reinterpret_cast<s16x4*>(&B1[o1]) = h4;
        }
    }
}

// ---------------- summary (mean over SEG rows, fp32 source) -> bf16 ----------
__global__ __launch_bounds__(256) void summary3_kernel(const float* __restrict__ qxF,
                                                       ushort* __restrict__ qxB) {
    int nb = blockIdx.x;          // N*B = 32
    int n = nb >> 1, b = nb & 1;
    int t = threadIdx.x;
    float acc[4] = {0.f, 0.f, 0.f, 0.f};
    for (int s = 0; s < SEG; ++s) {
        size_t base = ((size_t)((R + n * SEG + s) * B + b)) * D + t * 4;
        float4 x = *reinterpret_cast<const float4*>(&qxF[base]);
        acc[0] += x.x; acc[1] += x.y; acc[2] += x.z; acc[3] += x.w;
    }
    s16x4 h4;
    #pragma unroll
    for (int j = 0; j < 4; ++j) h4[j] = (short)bf16rne(acc[j] * (1.0f / SEG));
    size_t dst = ((size_t)(RT * B + nb)) * D + t * 4;
    *reinterpret_cast<s16x4*>(&qxB[dst]) = h4;
}

// ---------------- bf16 MFMA GEMM (m97 structure, 128x128, BK=32) --------------
__global__ __launch_bounds__(256) void gemm_bf(const ushort* __restrict__ A,
                                               const ushort* __restrict__ W,
                                               const float* __restrict__ bias,
                                               const float* __restrict__ residual,
                                               float* __restrict__ C,
                                               ushort* __restrict__ CB,
                                               int Mr, int Nc, int Kd,
                                               float alpha, int do_relu, int gx) {
    __shared__ __align__(16) ushort sm[2 * 4096];   // A | W (16 KB)
    ushort* sA = sm;
    ushort* sW = sm + 4096;

    // bijective XCD-chunk swizzle (T1/m204)
    int bid = blockIdx.x;
    int nwg = gridDim.x;
    int q8 = nwg >> 3, r8 = nwg & 7;
    int c8 = bid & 7, j8 = bid >> 3;
    int lin = (c8 < r8 ? c8 * (q8 + 1) : r8 * (q8 + 1) + (c8 - r8) * q8) + j8;
    const int bn0 = (lin % gx) * 128;
    const int bm0 = (lin / gx) * 128;

    const int t = threadIdx.x;
    const int w = t >> 6, lane = t & 63;
    const int wr = w >> 1, wc = w & 1;
    const int fr = lane & 15, fq = lane >> 4;

    const int srow = lane >> 2;
    const int scol = (lane & 3) * 8;
    const size_t aR0 = (size_t)(bm0 + w * 32 + srow) * Kd + scol;
    const size_t aR1 = aR0 + (size_t)16 * Kd;
    const size_t wR0 = (size_t)(bn0 + w * 32 + srow) * Kd + scol;
    const size_t wR1 = wR0 + (size_t)16 * Kd;
    const int lbase = w * 1024;

    f32x4 acc[4][4];
    #pragma unroll
    for (int m = 0; m < 4; ++m)
        #pragma unroll
        for (int n = 0; n < 4; ++n) acc[m][n] = f32x4{0.f, 0.f, 0.f, 0.f};

    const int ao = (wr * 64 + fr) * 32 + fq * 8;
    const int wo = (wc * 64 + fr) * 32 + fq * 8;

    for (int k0 = 0; k0 < Kd; k0 += 32) {
        gload16(A + aR0 + k0, sA + lbase);
        gload16(A + aR1 + k0, sA + lbase + 512);
        gload16(W + wR0 + k0, sW + lbase);
        gload16(W + wR1 + k0, sW + lbase + 512);
        __syncthreads();

        bf16x8 bh[4];
        #pragma unroll
        for (int n = 0; n < 4; ++n)
            bh[n] = *reinterpret_cast<const bf16x8*>(&sW[wo + n * 512]);
        #pragma unroll
        for (int m = 0; m < 4; ++m) {
            bf16x8 ah = *reinterpret_cast<const bf16x8*>(&sA[ao + m * 512]);
            #pragma unroll
            for (int n = 0; n < 4; ++n)
                acc[m][n] = __builtin_amdgcn_mfma_f32_16x16x32_bf16(ah, bh[n], acc[m][n], 0, 0, 0);
        }
        __syncthreads();
    }

    float bv[4];
    #pragma unroll
    for (int n = 0; n < 4; ++n) bv[n] = bias[bn0 + wc * 64 + n * 16 + fr];
    #pragma unroll
    for (int m = 0; m < 4; ++m) {
        #pragma unroll
        for (int j = 0; j < 4; ++j) {
            int row = bm0 + wr * 64 + m * 16 + fq * 4 + j;
            if (row < Mr) {
                #pragma unroll
                for (int n = 0; n < 4; ++n) {
                    int col = bn0 + wc * 64 + n * 16 + fr;
                    float v = (acc[m][n][j] + bv[n]) * alpha;
                    if (do_relu) v = fmaxf(v, 0.f);
                    if (residual) v += residual[(size_t)row * Nc + col];
                    if (CB) CB[(size_t)row * Nc + col] = bf16rne(v);
                    else    C[(size_t)row * Nc + col] = v;
                }
            }
        }
    }
}

// ---------------- sparse masked attention v4: f16 + v_dot2, 4 rows/iter ------
// 1024 blocks = (b,h,i,half). K f16 [c][64] XOR-swizzled; V f16 [d][c] XOR-
// swizzled; ps f16. All dot products via fdot2 (2 MAC/instr, f32 accum).
constexpr int CMX = 192;

__global__ __launch_bounds__(256) void attn4(const float* __restrict__ qb,
                                             const float* __restrict__ kvbuf,
                                             const int* __restrict__ lengths,
                                             ushort* __restrict__ outB) {
    __shared__ __align__(16) ushort K2[CMX * 64];     // [c][d] f16, 24576 B
    __shared__ __align__(16) ushort Vt[64 * CMX];     // [d][c] f16, 24576 B
    __shared__ __align__(16) ushort ps[4][4][CMX];    // 6144 B
    __shared__ __align__(16) ushort qs[4][4][64];     // 2048 B
    __shared__ int colmap[CMX];                       // 768 B -> ~58 KB total

    int gid = blockIdx.x;
    int half = gid & 1;
    int i = (gid >> 1) & 15;
    int h = (gid >> 5) & 15;
    int b = gid >> 9;
    int t = threadIdx.x;
    int lane = t & 63, w = t >> 6;

    int nm = i;
    int u0 = (i * SEG - L > 0) ? (i * SEG - L) : 0;
    int nc = nm + RCL + (i + 1) * SEG - u0;
    int nc4 = (nc + 7) & ~7;

    int maxlen = max(lengths[0], lengths[1]);
    int kl = lengths[b] + (M + R + T) - maxlen;

    for (int c = t; c < nc; c += 256) {
        int g;
        if (c < nm)            g = c;
        else if (c < nm + RCL) g = M + i * RCL + (c - nm);
        else                   g = M + R + u0 + (c - nm - RCL);
        colmap[c] = g;
    }
    __syncthreads();

    // stage K (f16 [c][64], 16B-slot XOR by c&7) and V (f16 [d][c], XOR by d&7)
    for (int f = t; f < nc * 16; f += 256) {
        int c = f >> 4, dc = f & 15;
        int g = colmap[c];
        size_t base = ((size_t)g * B + b) * KVSTR + h * 64 + dc * 4;
        float4 k4 = *reinterpret_cast<const float4*>(&kvbuf[base]);
        float4 v4 = *reinterpret_cast<const float4*>(&kvbuf[base + 1024]);
        us4 kh = {(ushort)f2h(k4.x), (ushort)f2h(k4.y), (ushort)f2h(k4.z), (ushort)f2h(k4.w)};
        *reinterpret_cast<us4*>((char*)K2 + c * 128 + ((dc * 8) ^ ((c & 7) << 4))) = kh;
        int d0 = dc * 4;
        *(ushort*)((char*)Vt + (d0 + 0) * 384 + ((c * 2) ^ (((d0 + 0) & 7) << 4))) = f2h(v4.x);
        *(ushort*)((char*)Vt + (d0 + 1) * 384 + ((c * 2) ^ (((d0 + 1) & 7) << 4))) = f2h(v4.y);
        *(ushort*)((char*)Vt + (d0 + 2) * 384 + ((c * 2) ^ (((d0 + 2) & 7) << 4))) = f2h(v4.z);
        *(ushort*)((char*)Vt + (d0 + 3) * 384 + ((c * 2) ^ (((d0 + 3) & 7) << 4))) = f2h(v4.w);
    }
    // zero V pad columns [nc, nc4) so p=0 * V never hits garbage NaN
    for (int f = t; f < 512; f += 256) {
        int c = nc + (f & 7), d = f >> 3;
        if (c < nc4)
            *(ushort*)((char*)Vt + d * 384 + ((c * 2) ^ ((d & 7) << 4))) = 0;
    }
    __syncthreads();

    const int nrows = half ? 65 : 68;
    const int rbase = half ? 68 : 0;
    const int c0 = lane, c1 = lane + 64, c2 = lane + 128;
    bool v0 = (c0 < nc) && (colmap[c0] < kl);
    bool v1 = (c1 < nc) && (colmap[c1] < kl);
    bool v2 = (c2 < nc) && (colmap[c2] < kl);
    const int xm0 = (c0 & 7) << 4, xm1 = (c1 & 7) << 4, xm2 = (c2 & 7) << 4;

    for (int rl = w * 4; rl < nrows; rl += 16) {
        int qrow[4]; bool rv[4];
        #pragma unroll
        for (int j = 0; j < 4; ++j) {
            int r = rl + j;
            rv[j] = (r < nrows);
            int rr = rbase + (rv[j] ? r : rl);
            qrow[j] = (rr < RCL) ? i * RCL + rr
                    : (rr < 132) ? R + i * SEG + (rr - RCL)
                                 : R + T + i;
        }
        #pragma unroll
        for (int j = 0; j < 4; ++j)
            qs[w][j][lane] = f2h(qb[((size_t)qrow[j] * B + b) * D + h * 64 + lane]);
        asm volatile("" ::: "memory");

        float a[4][3];
        #pragma unroll
        for (int r = 0; r < 4; ++r) { a[r][0] = 0.f; a[r][1] = 0.f; a[r][2] = 0.f; }

        #pragma unroll
        for (int j8 = 0; j8 < 8; ++j8) {
            u32x4 kk0 = *reinterpret_cast<const u32x4*>((char*)K2 + c0 * 128 + ((j8 * 16) ^ xm0));
            u32x4 kk1 = *reinterpret_cast<const u32x4*>((char*)K2 + c1 * 128 + ((j8 * 16) ^ xm1));
            u32x4 kk2 = *reinterpret_cast<const u32x4*>((char*)K2 + c2 * 128 + ((j8 * 16) ^ xm2));
            #pragma unroll
            for (int r = 0; r < 4; ++r) {
                u32x4 qq = *reinterpret_cast<const u32x4*>(&qs[w][r][j8 * 8]);
                #pragma unroll
                for (int e = 0; e < 4; ++e) {
                    a[r][0] = FDOT2(uh2(qq[e]), uh2(kk0[e]), a[r][0]);
                    a[r][1] = FDOT2(uh2(qq[e]), uh2(kk1[e]), a[r][1]);
                    a[r][2] = FDOT2(uh2(qq[e]), uh2(kk2[e]), a[r][2]);
                }
            }
        }

        float p[4][3], mrow[4], sum[4];
        #pragma unroll
        for (int r = 0; r < 4; ++r) {
            float s0 = v0 ? a[r][0] : -1e30f;
            float s1 = v1 ? a[r][1] : -1e30f;
            float s2 = v2 ? a[r][2] : -1e30f;
            a[r][0] = s0; a[r][1] = s1; a[r][2] = s2;
            mrow[r] = fmaxf(fmaxf(s0, s1), s2);
        }
        #pragma unroll
        for (int off = 32; off > 0; off >>= 1) {
            #pragma unroll
            for (int r = 0; r < 4; ++r)
                mrow[r] = fmaxf(mrow[r], __shfl_xor(mrow[r], off, 64));
        }
        #pragma unroll
        for (int r = 0; r < 4; ++r) {
            p[r][0] = __expf(a[r][0] - mrow[r]);
            p[r][1] = __expf(a[r][1] - mrow[r]);
            p[r][2] = __expf(a[r][2] - mrow[r]);
            sum[r] = p[r][0] + p[r][1] + p[r][2];
        }
        #pragma unroll
        for (int off = 32; off > 0; off >>= 1) {
            #pragma unroll
            for (int r = 0; r < 4; ++r)
                sum[r] += __shfl_xor(sum[r], off, 64);
        }
        #pragma unroll
        for (int r = 0; r < 4; ++r) {
            ps[w][r][c0] = f2h(p[r][0]);
            ps[w][r][c1] = f2h(p[r][1]);
            ps[w][r][c2] = f2h(p[r][2]);
        }
        asm volatile("" ::: "memory");

        float o[4] = {0.f, 0.f, 0.f, 0.f};
        const char* vrow = (const char*)Vt + lane * 384;
        const int xmv = (lane & 7) << 4;
        for (int c = 0; c < nc4; c += 8) {
            u32x4 vv = *reinterpret_cast<const u32x4*>(vrow + ((c * 2) ^ xmv));
            #pragma unroll
            for (int r = 0; r < 4; ++r) {
                u32x4 pp = *reinterpret_cast<const u32x4*>(&ps[w][r][c]);
                o[r] = FDOT2(uh2(pp[0]), uh2(vv[0]), o[r]);
                o[r] = FDOT2(uh2(pp[1]), uh2(vv[1]), o[r]);
                o[r] = FDOT2(uh2(pp[2]), uh2(vv[2]), o[r]);
                o[r] = FDOT2(uh2(pp[3]), uh2(vv[3]), o[r]);
            }
        }
        #pragma unroll
        for (int r = 0; r < 4; ++r) {
            if (rv[r]) {
                size_t ob = ((size_t)qrow[r] * B + b) * D + h * 64 + lane;
                outB[ob] = bf16rne(o[r] / sum[r]);
            }
        }
    }
}

// ---------------- residual add + mems clip ----------------
__global__ __launch_bounds__(256) void resid_clip(const float* __restrict__ obuf,
                                                  const float* __restrict__ rc,
                                                  const float* __restrict__ utt,
                                                  float* __restrict__ result,
                                                  float* __restrict__ out_mems) {
    size_t idx = (size_t)blockIdx.x * 256 + threadIdx.x;
    size_t f = idx * 4;
    if (f >= (size_t)Q * B * D) return;
    int row = (int)(f >> 10);
    float4 o = *reinterpret_cast<const float4*>(&obuf[f]);
    if (row < RT * B) {
        const float* res = (row < R * B) ? &rc[f] : &utt[f - (size_t)R * B * D];
        float4 rv = *reinterpret_cast<const float4*>(res);
        o.x += rv.x; o.y += rv.y; o.z += rv.z; o.w += rv.w;
        *reinterpret_cast<float4*>(&result[f]) = o;
    } else {
        o.x = fminf(fmaxf(o.x, -10.f), 10.f);
        o.y = fminf(fmaxf(o.y, -10.f), 10.f);
        o.z = fminf(fmaxf(o.z, -10.f), 10.f);
        o.w = fminf(fmaxf(o.w, -10.f), 10.f);
        *reinterpret_cast<float4*>(&out_mems[f - (size_t)RT * B * D]) = o;
    }
}

// ---------------- launch ----------------
extern "C" void kernel_launch(void* const* d_in, const int* in_sizes, int n_in,
                              void* d_out, int out_size, void* d_ws, size_t ws_size,
                              hipStream_t stream) {
    const float* utt   = (const float*)d_in[0];
    const float* rc    = (const float*)d_in[1];
    const float* mems  = (const float*)d_in[2];
    const float* lng   = (const float*)d_in[3];
    const float* lnb   = (const float*)d_in[4];
    const float* Wq    = (const float*)d_in[5];
    const float* bq    = (const float*)d_in[6];
    const float* Wkv   = (const float*)d_in[7];
    const float* bkv   = (const float*)d_in[8];
    const float* Wo    = (const float*)d_in[9];
    const float* bo    = (const float*)d_in[10];
    const float* ffg   = (const float*)d_in[11];
    const float* ffb   = (const float*)d_in[12];
    const float* W1    = (const float*)d_in[13];
    const float* b1    = (const float*)d_in[14];
    const float* W2    = (const float*)d_in[15];
    const float* b2    = (const float*)d_in[16];
    const float* outg  = (const float*)d_in[17];
    const float* outb  = (const float*)d_in[18];
    const int*   lens  = (const int*)d_in[19];

    constexpr int QBD  = Q * B * D;    // 4256 rows x 1024
    constexpr int KVBD = KV * B * D;   // 4254 rows x 1024

    float* ws = (float*)d_ws;
    size_t off = 0;
    auto allocF = [&](size_t n) { float* p = ws + off; off += (n + 63) & ~(size_t)63; return p; };
    auto allocU = [&](size_t n) { ushort* p = (ushort*)(ws + off); off += ((n + 1) / 2 + 63) & ~(size_t)63; return p; };

    float* f_q   = allocF(QBD);                 // q proj (4256 rows)
    float* f_kv  = allocF((size_t)KVBD * 2);    // fused k|v proj [4254][2048]
    float* qxF   = allocF((size_t)RT * B * D);  // fp32 input-LN copy for summary
    ushort* qxB  = allocU((size_t)MPAD * D);
    ushort* kvB  = allocU((size_t)MPAD * D);
    ushort* atB  = allocU((size_t)MPAD * D);
    ushort* flB  = allocU((size_t)RT * B * D);
    ushort* fhB  = allocU((size_t)RT * B * FFN);
    ushort* wAll = allocU((size_t)4 * D * D + 2 * (size_t)FFN * D);
    // fp32 aliases — row-capacity checked:
    float* obuf   = f_q;                        // 4256 rows <= 4256 ✓ (q consumed by attn)
    float* result = f_kv;                       // 4224 rows x 1024 in lower half ✓
    float* res2   = f_kv + (size_t)RT * B * D;  // disjoint upper region ✓
    float* out = (float*)d_out;

    const ushort* wq  = wAll;
    const ushort* wkv = wAll + (size_t)D * D;
    const ushort* wo  = wAll + (size_t)3 * D * D;
    const ushort* w1  = wAll + (size_t)4 * D * D;
    const ushort* w2  = wAll + (size_t)4 * D * D + (size_t)FFN * D;

    auto gemm = [&](const ushort* a, const ushort* wgt, const float* bias,
                    const float* resid, float* C, ushort* CB,
                    int Mr, int Mpad, int Nc, int Kd, float alpha, int relu) {
        int gx = Nc / 128, gy = Mpad / 128;
        gemm_bf<<<gx * gy, 256, 0, stream>>>(a, wgt, bias, resid, C, CB,
                                             Mr, Nc, Kd, alpha, relu, gx);
    };

    // 0. prep: all weight converts + mems + pad zeroing (one kernel)
    {
        constexpr int n8 = 4 * D * D / 4 + 2 * FFN * D / 4 + M * B * D / 4
                         + 2 * (MPAD - Q * B) * D / 4 + (MPAD - KV * B) * D / 4;
        prep_kernel<<<(n8 + 255) / 256, 256, 0, stream>>>(Wq, Wkv, Wo, W1, W2, mems,
                                                          wAll, kvB, qxB, atB);
    }
    // 1. input LN -> qxF (fp32) + qxB rows [0,RT*B) + kvB rows [M*B, KV*B)
    ln2_kernel<<<RT * B, 256, 0, stream>>>(rc, utt, R * B, qxF, 0,
                                           qxB, kvB, M * B, lng, lnb);
    // 2. summary (fp32 source) -> qxB rows [RT*B, Q*B)
    summary3_kernel<<<N * B, 256, 0, stream>>>(qxF, qxB);
    // 3. q projection (scaled)
    gemm(qxB, wq, bq, nullptr, f_q, nullptr, Q * B, MPAD, D, D, 0.125f, 0);
    // 4. fused k|v projection -> f_kv [4254][2048]
    gemm(kvB, wkv, bkv, nullptr, f_kv, nullptr, KV * B, MPAD, KVSTR, D, 1.0f, 0);
    // 5. sparse attention -> atB (bf16)
    attn4<<<N * B * H * 2, 256, 0, stream>>>(f_q, f_kv, lens, atB);
    // 6. output projection -> obuf (= f_q; q consumed)
    gemm(atB, wo, bo, nullptr, obuf, nullptr, Q * B, MPAD, D, D, 1.0f, 0);
    // 7. residual + mems clip
    resid_clip<<<(Q * B * D / 4 + 255) / 256, 256, 0, stream>>>(
        obuf, rc, utt, result, out + (size_t)(T + R) * B * D);
    // 8. FFN input LN -> flB
    ln2_kernel<<<RT * B, 256, 0, stream>>>(result, result, RT * B, nullptr, 0,
                                           flB, nullptr, 0, ffg, ffb);
    // 9. FFN up + relu -> fhB (bf16 epilogue)
    gemm(flB, w1, b1, nullptr, nullptr, fhB, RT * B, RT * B, FFN, D, 1.0f, 1);
    // 10. FFN down + residual -> res2
    gemm(fhB, w2, b2, result, res2, nullptr, RT * B, RT * B, D, FFN, 1.0f, 0);
    // 11. output LN with row remap -> out
    ln2_kernel<<<RT * B, 256, 0, stream>>>(res2, res2, RT * B, out, 1,
                                           nullptr, nullptr, 0, outg, outb);
}

// Round 9
// 531.291 us; speedup vs baseline: 4.8533x; 1.0993x over previous
//
#include <hip/hip_runtime.h>

// ---------------- problem constants ----------------
constexpr int D   = 1024;
constexpr int H   = 16;
constexpr int FFN = 4096;
constexpr int SEG = 128;
constexpr int L   = 32;
constexpr int RCL = 4;
constexpr int T   = 2048;
constexpr int B   = 2;
constexpr int N   = T / SEG;   // 16
constexpr int M   = N - 1;     // 15
constexpr int R   = RCL * N;   // 64
constexpr int Q   = R + T + N; // 2128
constexpr int KV  = M + R + T; // 2127
constexpr int RT  = R + T;     // 2112
constexpr float EPS = 1e-5f;
constexpr int MPAD = 4352;     // ceil(4256/128)*128
constexpr int KVSTR = 2048;    // fused k|v projection row stride

typedef float f32x4 __attribute__((ext_vector_type(4)));
typedef __bf16 bf16x8 __attribute__((ext_vector_type(8)));
typedef short s16x4 __attribute__((ext_vector_type(4)));
typedef unsigned u32x4 __attribute__((ext_vector_type(4)));
typedef ushort us4 __attribute__((ext_vector_type(4)));
typedef _Float16 h2_t __attribute__((ext_vector_type(2)));

// ---------------- helpers ----------------
__device__ __forceinline__ ushort bf16rne(float x) {
    unsigned u = __float_as_uint(x);
    return (ushort)((u + 0x7FFFu + ((u >> 16) & 1u)) >> 16);
}
__device__ __forceinline__ ushort f2h(float x) {
    _Float16 h = (_Float16)x;
    ushort u; __builtin_memcpy(&u, &h, 2); return u;
}
__device__ __forceinline__ h2_t uh2(unsigned u) {
    h2_t h; __builtin_memcpy(&h, &u, 4); return h;
}
#define FDOT2(a, b, c) __builtin_amdgcn_fdot2((a), (b), (c), false)

__device__ inline void block_reduce_2(float& s1, float& s2) {
    #pragma unroll
    for (int off = 32; off > 0; off >>= 1) {
        s1 += __shfl_xor(s1, off, 64);
        s2 += __shfl_xor(s2, off, 64);
    }
    __shared__ float red[8];
    int lane = threadIdx.x & 63, w = threadIdx.x >> 6;
    if (lane == 0) { red[w * 2] = s1; red[w * 2 + 1] = s2; }
    __syncthreads();
    s1 = red[0] + red[2] + red[4] + red[6];
    s2 = red[1] + red[3] + red[5] + red[7];
}

// async global->LDS, 16B per lane; lds base must be wave-uniform
__device__ __forceinline__ void gload16(const void* g, void* l) {
    __builtin_amdgcn_global_load_lds(
        (__attribute__((address_space(1))) void*)(uintptr_t)g,
        (__attribute__((address_space(3))) void*)(unsigned)(uintptr_t)l,
        16, 0, 0);
}

// ---------------- prep: all weight/mems bf16 converts + pad zeroing, 1 kernel --
__global__ __launch_bounds__(256) void prep_kernel(const float* __restrict__ Wq,
                                                   const float* __restrict__ Wkv,
                                                   const float* __restrict__ Wo,
                                                   const float* __restrict__ W1,
                                                   const float* __restrict__ W2,
                                                   const float* __restrict__ mems,
                                                   ushort* __restrict__ wAll,
                                                   ushort* __restrict__ kvB,
                                                   ushort* __restrict__ qxB,
                                                   ushort* __restrict__ atB) {
    int idx = blockIdx.x * 256 + threadIdx.x;
    constexpr int n0 = D * D / 4;                 // Wq
    constexpr int n1 = n0 + 2 * D * D / 4;        // Wkv
    constexpr int n2 = n1 + D * D / 4;            // Wo
    constexpr int n3 = n2 + FFN * D / 4;          // W1
    constexpr int n4 = n3 + FFN * D / 4;          // W2
    constexpr int n5 = n4 + M * B * D / 4;        // mems -> kvB rows [0, M*B)
    constexpr int n6 = n5 + (MPAD - Q * B) * D / 4;   // qxB pad
    constexpr int n7 = n6 + (MPAD - KV * B) * D / 4;  // kvB pad
    constexpr int n8 = n7 + (MPAD - Q * B) * D / 4;   // atB pad
    if (idx >= n8) return;
    const float* src = nullptr; ushort* dst; int rel;
    if (idx < n0)      { src = Wq;   dst = wAll;                              rel = idx; }
    else if (idx < n1) { src = Wkv;  dst = wAll + D * D;                      rel = idx - n0; }
    else if (idx < n2) { src = Wo;   dst = wAll + 3 * D * D;                  rel = idx - n1; }
    else if (idx < n3) { src = W1;   dst = wAll + 4 * D * D;                  rel = idx - n2; }
    else if (idx < n4) { src = W2;   dst = wAll + 4 * D * D + FFN * D;        rel = idx - n3; }
    else if (idx < n5) { src = mems; dst = kvB;                               rel = idx - n4; }
    else if (idx < n6) { dst = qxB + (size_t)Q * B * D;                       rel = idx - n5; }
    else if (idx < n7) { dst = kvB + (size_t)KV * B * D;                      rel = idx - n6; }
    else               { dst = atB + (size_t)Q * B * D;                       rel = idx - n7; }
    s16x4 hv = {0, 0, 0, 0};
    if (src) {
        float4 x = *reinterpret_cast<const float4*>(&src[(size_t)rel * 4]);
        hv[0] = (short)bf16rne(x.x); hv[1] = (short)bf16rne(x.y);
        hv[2] = (short)bf16rne(x.z); hv[3] = (short)bf16rne(x.w);
    }
    *reinterpret_cast<s16x4*>(&dst[(size_t)rel * 4]) = hv;
}

// ---------------- LayerNorm with fused bf16 output ----------------
__global__ __launch_bounds__(256) void ln2_kernel(const float* __restrict__ src0,
                                                  const float* __restrict__ src1,
                                                  int split,
                                                  float* __restrict__ dstF, int remap,
                                                  ushort* __restrict__ B0,
                                                  ushort* __restrict__ B1,
                                                  int rowoff1,
                                                  const float* __restrict__ gamma,
                                                  const float* __restrict__ beta) {
    int row = blockIdx.x;
    int t = threadIdx.x;
    const float* src = (row < split) ? src0 + (size_t)row * D
                                     : src1 + (size_t)(row - split) * D;
    float4 x = *reinterpret_cast<const float4*>(&src[t * 4]);
    float s1 = x.x + x.y + x.z + x.w;
    float s2 = x.x * x.x + x.y * x.y + x.z * x.z + x.w * x.w;
    block_reduce_2(s1, s2);
    float mean = s1 * (1.0f / D);
    float var  = s2 * (1.0f / D) - mean * mean;
    float rs = rsqrtf(var + EPS);
    float4 g4 = *reinterpret_cast<const float4*>(&gamma[t * 4]);
    float4 b4 = *reinterpret_cast<const float4*>(&beta[t * 4]);
    float y[4];
    y[0] = (x.x - mean) * rs * g4.x + b4.x;
    y[1] = (x.y - mean) * rs * g4.y + b4.y;
    y[2] = (x.z - mean) * rs * g4.z + b4.z;
    y[3] = (x.w - mean) * rs * g4.w + b4.w;
    if (dstF) {
        size_t off;
        if (!remap) off = (size_t)row * D;
        else off = (row < R * B) ? ((size_t)T * B * D + (size_t)row * D)
                                 : ((size_t)(row - R * B) * D);
        *reinterpret_cast<float4*>(&dstF[off + t * 4]) =
            make_float4(y[0], y[1], y[2], y[3]);
    }
    if (B0) {
        s16x4 h4;
        #pragma unroll
        for (int j = 0; j < 4; ++j) h4[j] = (short)bf16rne(y[j]);
        size_t o0 = (size_t)row * D + t * 4;
        *reinterpret_cast<s16x4*>(&B0[o0]) = h4;
        if (B1) {
            size_t o1 = (size_t)(row + rowoff1) * D + t * 4;
            *reinterpret_cast<s16x4*>(&B1[o1]) = h4;
        }
    }
}

// ---------------- summary (mean over SEG rows, fp32 source) -> bf16 ----------
__global__ __launch_bounds__(256) void summary3_kernel(const float* __restrict__ qxF,
                                                       ushort* __restrict__ qxB) {
    int nb = blockIdx.x;          // N*B = 32
    int n = nb >> 1, b = nb & 1;
    int t = threadIdx.x;
    float acc[4] = {0.f, 0.f, 0.f, 0.f};
    for (int s = 0; s < SEG; ++s) {
        size_t base = ((size_t)((R + n * SEG + s) * B + b)) * D + t * 4;
        float4 x = *reinterpret_cast<const float4*>(&qxF[base]);
        acc[0] += x.x; acc[1] += x.y; acc[2] += x.z; acc[3] += x.w;
    }
    s16x4 h4;
    #pragma unroll
    for (int j = 0; j < 4; ++j) h4[j] = (short)bf16rne(acc[j] * (1.0f / SEG));
    size_t dst = ((size_t)(RT * B + nb)) * D + t * 4;
    *reinterpret_cast<s16x4*>(&qxB[dst]) = h4;
}

// ---------------- bf16 MFMA GEMM, double-buffered 2-phase (T3-minimal) --------
// Stage tile t+1 into alternate LDS buffer BEFORE computing tile t; single
// barrier per K-step. HBM/L2 latency hides under ds_read+MFMA of current tile.
__global__ __launch_bounds__(256) void gemm_bf(const ushort* __restrict__ A,
                                               const ushort* __restrict__ W,
                                               const float* __restrict__ bias,
                                               const float* __restrict__ residual,
                                               float* __restrict__ C,
                                               ushort* __restrict__ CB,
                                               int Mr, int Nc, int Kd,
                                               float alpha, int do_relu, int gx) {
    __shared__ __align__(16) ushort sm[2 * 8192];   // dbuf x (A 4096 | W 4096) = 32 KB

    // bijective XCD-chunk swizzle (T1/m204)
    int bid = blockIdx.x;
    int nwg = gridDim.x;
    int q8 = nwg >> 3, r8 = nwg & 7;
    int c8 = bid & 7, j8 = bid >> 3;
    int lin = (c8 < r8 ? c8 * (q8 + 1) : r8 * (q8 + 1) + (c8 - r8) * q8) + j8;
    const int bn0 = (lin % gx) * 128;
    const int bm0 = (lin / gx) * 128;

    const int t = threadIdx.x;
    const int w = t >> 6, lane = t & 63;
    const int wr = w >> 1, wc = w & 1;
    const int fr = lane & 15, fq = lane >> 4;

    const int srow = lane >> 2;
    const int scol = (lane & 3) * 8;
    const size_t aR0 = (size_t)(bm0 + w * 32 + srow) * Kd + scol;
    const size_t aR1 = aR0 + (size_t)16 * Kd;
    const size_t wR0 = (size_t)(bn0 + w * 32 + srow) * Kd + scol;
    const size_t wR1 = wR0 + (size_t)16 * Kd;
    const int lbase = w * 1024;

    f32x4 acc[4][4];
    #pragma unroll
    for (int m = 0; m < 4; ++m)
        #pragma unroll
        for (int n = 0; n < 4; ++n) acc[m][n] = f32x4{0.f, 0.f, 0.f, 0.f};

    const int ao = (wr * 64 + fr) * 32 + fq * 8;
    const int wo = (wc * 64 + fr) * 32 + fq * 8;

    auto stage = [&](int buf, int k0) {
        ushort* s = sm + buf * 8192;
        gload16(A + aR0 + k0, s + lbase);
        gload16(A + aR1 + k0, s + lbase + 512);
        gload16(W + wR0 + k0, s + 4096 + lbase);
        gload16(W + wR1 + k0, s + 4096 + lbase + 512);
    };

    const int nt = Kd >> 5;
    stage(0, 0);
    __syncthreads();               // drains vmcnt -> buf0 ready
    int cur = 0;
    for (int kt = 0; kt < nt; ++kt) {
        if (kt + 1 < nt) stage(cur ^ 1, (kt + 1) * 32);   // overlap with compute
        const ushort* sA = sm + cur * 8192;
        const ushort* sW = sA + 4096;
        bf16x8 bh[4];
        #pragma unroll
        for (int n = 0; n < 4; ++n)
            bh[n] = *reinterpret_cast<const bf16x8*>(&sW[wo + n * 512]);
        #pragma unroll
        for (int m = 0; m < 4; ++m) {
            bf16x8 ah = *reinterpret_cast<const bf16x8*>(&sA[ao + m * 512]);
            #pragma unroll
            for (int n = 0; n < 4; ++n)
                acc[m][n] = __builtin_amdgcn_mfma_f32_16x16x32_bf16(ah, bh[n], acc[m][n], 0, 0, 0);
        }
        __syncthreads();           // all reads of cur done; next buf staged
        cur ^= 1;
    }

    // epilogue: C/D layout col=lane&15, row=(lane>>4)*4+j  [m89-verified]
    float bv[4];
    #pragma unroll
    for (int n = 0; n < 4; ++n) bv[n] = bias[bn0 + wc * 64 + n * 16 + fr];
    #pragma unroll
    for (int m = 0; m < 4; ++m) {
        #pragma unroll
        for (int j = 0; j < 4; ++j) {
            int row = bm0 + wr * 64 + m * 16 + fq * 4 + j;
            if (row < Mr) {
                #pragma unroll
                for (int n = 0; n < 4; ++n) {
                    int col = bn0 + wc * 64 + n * 16 + fr;
                    float v = (acc[m][n][j] + bv[n]) * alpha;
                    if (do_relu) v = fmaxf(v, 0.f);
                    if (residual) v += residual[(size_t)row * Nc + col];
                    if (CB) CB[(size_t)row * Nc + col] = bf16rne(v);
                    else    C[(size_t)row * Nc + col] = v;
                }
            }
        }
    }
}

// ---------------- sparse masked attention v4: f16 + v_dot2, 4 rows/iter ------
// (byte-identical to r7's passing version)
constexpr int CMX = 192;

__global__ __launch_bounds__(256) void attn4(const float* __restrict__ qb,
                                             const float* __restrict__ kvbuf,
                                             const int* __restrict__ lengths,
                                             ushort* __restrict__ outB) {
    __shared__ __align__(16) ushort K2[CMX * 64];     // [c][d] f16, 24576 B
    __shared__ __align__(16) ushort Vt[64 * CMX];     // [d][c] f16, 24576 B
    __shared__ __align__(16) ushort ps[4][4][CMX];    // 6144 B
    __shared__ __align__(16) ushort qs[4][4][64];     // 2048 B
    __shared__ int colmap[CMX];                       // 768 B -> ~58 KB total

    int gid = blockIdx.x;
    int half = gid & 1;
    int i = (gid >> 1) & 15;
    int h = (gid >> 5) & 15;
    int b = gid >> 9;
    int t = threadIdx.x;
    int lane = t & 63, w = t >> 6;

    int nm = i;
    int u0 = (i * SEG - L > 0) ? (i * SEG - L) : 0;
    int nc = nm + RCL + (i + 1) * SEG - u0;
    int nc4 = (nc + 7) & ~7;

    int maxlen = max(lengths[0], lengths[1]);
    int kl = lengths[b] + (M + R + T) - maxlen;

    for (int c = t; c < nc; c += 256) {
        int g;
        if (c < nm)            g = c;
        else if (c < nm + RCL) g = M + i * RCL + (c - nm);
        else                   g = M + R + u0 + (c - nm - RCL);
        colmap[c] = g;
    }
    __syncthreads();

    // stage K (f16 [c][64], 16B-slot XOR by c&7) and V (f16 [d][c], XOR by d&7)
    for (int f = t; f < nc * 16; f += 256) {
        int c = f >> 4, dc = f & 15;
        int g = colmap[c];
        size_t base = ((size_t)g * B + b) * KVSTR + h * 64 + dc * 4;
        float4 k4 = *reinterpret_cast<const float4*>(&kvbuf[base]);
        float4 v4 = *reinterpret_cast<const float4*>(&kvbuf[base + 1024]);
        us4 kh = {(ushort)f2h(k4.x), (ushort)f2h(k4.y), (ushort)f2h(k4.z), (ushort)f2h(k4.w)};
        *reinterpret_cast<us4*>((char*)K2 + c * 128 + ((dc * 8) ^ ((c & 7) << 4))) = kh;
        int d0 = dc * 4;
        *(ushort*)((char*)Vt + (d0 + 0) * 384 + ((c * 2) ^ (((d0 + 0) & 7) << 4))) = f2h(v4.x);
        *(ushort*)((char*)Vt + (d0 + 1) * 384 + ((c * 2) ^ (((d0 + 1) & 7) << 4))) = f2h(v4.y);
        *(ushort*)((char*)Vt + (d0 + 2) * 384 + ((c * 2) ^ (((d0 + 2) & 7) << 4))) = f2h(v4.z);
        *(ushort*)((char*)Vt + (d0 + 3) * 384 + ((c * 2) ^ (((d0 + 3) & 7) << 4))) = f2h(v4.w);
    }
    // zero V pad columns [nc, nc4) so p=0 * V never hits garbage NaN
    for (int f = t; f < 512; f += 256) {
        int c = nc + (f & 7), d = f >> 3;
        if (c < nc4)
            *(ushort*)((char*)Vt + d * 384 + ((c * 2) ^ ((d & 7) << 4))) = 0;
    }
    __syncthreads();

    const int nrows = half ? 65 : 68;
    const int rbase = half ? 68 : 0;
    const int c0 = lane, c1 = lane + 64, c2 = lane + 128;
    bool v0 = (c0 < nc) && (colmap[c0] < kl);
    bool v1 = (c1 < nc) && (colmap[c1] < kl);
    bool v2 = (c2 < nc) && (colmap[c2] < kl);
    const int xm0 = (c0 & 7) << 4, xm1 = (c1 & 7) << 4, xm2 = (c2 & 7) << 4;

    for (int rl = w * 4; rl < nrows; rl += 16) {
        int qrow[4]; bool rv[4];
        #pragma unroll
        for (int j = 0; j < 4; ++j) {
            int r = rl + j;
            rv[j] = (r < nrows);
            int rr = rbase + (rv[j] ? r : rl);
            qrow[j] = (rr < RCL) ? i * RCL + rr
                    : (rr < 132) ? R + i * SEG + (rr - RCL)
                                 : R + T + i;
        }
        #pragma unroll
        for (int j = 0; j < 4; ++j)
            qs[w][j][lane] = f2h(qb[((size_t)qrow[j] * B + b) * D + h * 64 + lane]);
        asm volatile("" ::: "memory");

        float a[4][3];
        #pragma unroll
        for (int r = 0; r < 4; ++r) { a[r][0] = 0.f; a[r][1] = 0.f; a[r][2] = 0.f; }

        #pragma unroll
        for (int j8 = 0; j8 < 8; ++j8) {
            u32x4 kk0 = *reinterpret_cast<const u32x4*>((char*)K2 + c0 * 128 + ((j8 * 16) ^ xm0));
            u32x4 kk1 = *reinterpret_cast<const u32x4*>((char*)K2 + c1 * 128 + ((j8 * 16) ^ xm1));
            u32x4 kk2 = *reinterpret_cast<const u32x4*>((char*)K2 + c2 * 128 + ((j8 * 16) ^ xm2));
            #pragma unroll
            for (int r = 0; r < 4; ++r) {
                u32x4 qq = *reinterpret_cast<const u32x4*>(&qs[w][r][j8 * 8]);
                #pragma unroll
                for (int e = 0; e < 4; ++e) {
                    a[r][0] = FDOT2(uh2(qq[e]), uh2(kk0[e]), a[r][0]);
                    a[r][1] = FDOT2(uh2(qq[e]), uh2(kk1[e]), a[r][1]);
                    a[r][2] = FDOT2(uh2(qq[e]), uh2(kk2[e]), a[r][2]);
                }
            }
        }

        float p[4][3], mrow[4], sum[4];
        #pragma unroll
        for (int r = 0; r < 4; ++r) {
            float s0 = v0 ? a[r][0] : -1e30f;
            float s1 = v1 ? a[r][1] : -1e30f;
            float s2 = v2 ? a[r][2] : -1e30f;
            a[r][0] = s0; a[r][1] = s1; a[r][2] = s2;
            mrow[r] = fmaxf(fmaxf(s0, s1), s2);
        }
        #pragma unroll
        for (int off = 32; off > 0; off >>= 1) {
            #pragma unroll
            for (int r = 0; r < 4; ++r)
                mrow[r] = fmaxf(mrow[r], __shfl_xor(mrow[r], off, 64));
        }
        #pragma unroll
        for (int r = 0; r < 4; ++r) {
            p[r][0] = __expf(a[r][0] - mrow[r]);
            p[r][1] = __expf(a[r][1] - mrow[r]);
            p[r][2] = __expf(a[r][2] - mrow[r]);
            sum[r] = p[r][0] + p[r][1] + p[r][2];
        }
        #pragma unroll
        for (int off = 32; off > 0; off >>= 1) {
            #pragma unroll
            for (int r = 0; r < 4; ++r)
                sum[r] += __shfl_xor(sum[r], off, 64);
        }
        #pragma unroll
        for (int r = 0; r < 4; ++r) {
            ps[w][r][c0] = f2h(p[r][0]);
            ps[w][r][c1] = f2h(p[r][1]);
            ps[w][r][c2] = f2h(p[r][2]);
        }
        asm volatile("" ::: "memory");

        float o[4] = {0.f, 0.f, 0.f, 0.f};
        const char* vrow = (const char*)Vt + lane * 384;
        const int xmv = (lane & 7) << 4;
        for (int c = 0; c < nc4; c += 8) {
            u32x4 vv = *reinterpret_cast<const u32x4*>(vrow + ((c * 2) ^ xmv));
            #pragma unroll
            for (int r = 0; r < 4; ++r) {
                u32x4 pp = *reinterpret_cast<const u32x4*>(&ps[w][r][c]);
                o[r] = FDOT2(uh2(pp[0]), uh2(vv[0]), o[r]);
                o[r] = FDOT2(uh2(pp[1]), uh2(vv[1]), o[r]);
                o[r] = FDOT2(uh2(pp[2]), uh2(vv[2]), o[r]);
                o[r] = FDOT2(uh2(pp[3]), uh2(vv[3]), o[r]);
            }
        }
        #pragma unroll
        for (int r = 0; r < 4; ++r) {
            if (rv[r]) {
                size_t ob = ((size_t)qrow[r] * B + b) * D + h * 64 + lane;
                outB[ob] = bf16rne(o[r] / sum[r]);
            }
        }
    }
}

// ---------------- residual add + mems clip ----------------
__global__ __launch_bounds__(256) void resid_clip(const float* __restrict__ obuf,
                                                  const float* __restrict__ rc,
                                                  const float* __restrict__ utt,
                                                  float* __restrict__ result,
                                                  float* __restrict__ out_mems) {
    size_t idx = (size_t)blockIdx.x * 256 + threadIdx.x;
    size_t f = idx * 4;
    if (f >= (size_t)Q * B * D) return;
    int row = (int)(f >> 10);
    float4 o = *reinterpret_cast<const float4*>(&obuf[f]);
    if (row < RT * B) {
        const float* res = (row < R * B) ? &rc[f] : &utt[f - (size_t)R * B * D];
        float4 rv = *reinterpret_cast<const float4*>(res);
        o.x += rv.x; o.y += rv.y; o.z += rv.z; o.w += rv.w;
        *reinterpret_cast<float4*>(&result[f]) = o;
    } else {
        o.x = fminf(fmaxf(o.x, -10.f), 10.f);
        o.y = fminf(fmaxf(o.y, -10.f), 10.f);
        o.z = fminf(fmaxf(o.z, -10.f), 10.f);
        o.w = fminf(fmaxf(o.w, -10.f), 10.f);
        *reinterpret_cast<float4*>(&out_mems[f - (size_t)RT * B * D]) = o;
    }
}

// ---------------- launch ----------------
extern "C" void kernel_launch(void* const* d_in, const int* in_sizes, int n_in,
                              void* d_out, int out_size, void* d_ws, size_t ws_size,
                              hipStream_t stream) {
    const float* utt   = (const float*)d_in[0];
    const float* rc    = (const float*)d_in[1];
    const float* mems  = (const float*)d_in[2];
    const float* lng   = (const float*)d_in[3];
    const float* lnb   = (const float*)d_in[4];
    const float* Wq    = (const float*)d_in[5];
    const float* bq    = (const float*)d_in[6];
    const float* Wkv   = (const float*)d_in[7];
    const float* bkv   = (const float*)d_in[8];
    const float* Wo    = (const float*)d_in[9];
    const float* bo    = (const float*)d_in[10];
    const float* ffg   = (const float*)d_in[11];
    const float* ffb   = (const float*)d_in[12];
    const float* W1    = (const float*)d_in[13];
    const float* b1    = (const float*)d_in[14];
    const float* W2    = (const float*)d_in[15];
    const float* b2    = (const float*)d_in[16];
    const float* outg  = (const float*)d_in[17];
    const float* outb  = (const float*)d_in[18];
    const int*   lens  = (const int*)d_in[19];

    constexpr int QBD  = Q * B * D;    // 4256 rows x 1024
    constexpr int KVBD = KV * B * D;   // 4254 rows x 1024

    float* ws = (float*)d_ws;
    size_t off = 0;
    auto allocF = [&](size_t n) { float* p = ws + off; off += (n + 63) & ~(size_t)63; return p; };
    auto allocU = [&](size_t n) { ushort* p = (ushort*)(ws + off); off += ((n + 1) / 2 + 63) & ~(size_t)63; return p; };

    float* f_q   = allocF(QBD);                 // q proj (4256 rows)
    float* f_kv  = allocF((size_t)KVBD * 2);    // fused k|v proj [4254][2048]
    float* qxF   = allocF((size_t)RT * B * D);  // fp32 input-LN copy for summary
    ushort* qxB  = allocU((size_t)MPAD * D);
    ushort* kvB  = allocU((size_t)MPAD * D);
    ushort* atB  = allocU((size_t)MPAD * D);
    ushort* flB  = allocU((size_t)RT * B * D);
    ushort* fhB  = allocU((size_t)RT * B * FFN);
    ushort* wAll = allocU((size_t)4 * D * D + 2 * (size_t)FFN * D);
    // fp32 aliases — row-capacity checked:
    float* obuf   = f_q;                        // 4256 rows <= 4256 ✓ (q consumed by attn)
    float* result = f_kv;                       // 4224 rows x 1024 in lower half ✓
    float* res2   = f_kv + (size_t)RT * B * D;  // disjoint upper region ✓
    float* out = (float*)d_out;

    const ushort* wq  = wAll;
    const ushort* wkv = wAll + (size_t)D * D;
    const ushort* wo  = wAll + (size_t)3 * D * D;
    const ushort* w1  = wAll + (size_t)4 * D * D;
    const ushort* w2  = wAll + (size_t)4 * D * D + (size_t)FFN * D;

    auto gemm = [&](const ushort* a, const ushort* wgt, const float* bias,
                    const float* resid, float* C, ushort* CB,
                    int Mr, int Mpad, int Nc, int Kd, float alpha, int relu) {
        int gx = Nc / 128, gy = Mpad / 128;
        gemm_bf<<<gx * gy, 256, 0, stream>>>(a, wgt, bias, resid, C, CB,
                                             Mr, Nc, Kd, alpha, relu, gx);
    };

    // 0. prep: all weight converts + mems + pad zeroing (one kernel)
    {
        constexpr int n8 = 4 * D * D / 4 + 2 * FFN * D / 4 + M * B * D / 4
                         + 2 * (MPAD - Q * B) * D / 4 + (MPAD - KV * B) * D / 4;
        prep_kernel<<<(n8 + 255) / 256, 256, 0, stream>>>(Wq, Wkv, Wo, W1, W2, mems,
                                                          wAll, kvB, qxB, atB);
    }
    // 1. input LN -> qxF (fp32) + qxB rows [0,RT*B) + kvB rows [M*B, KV*B)
    ln2_kernel<<<RT * B, 256, 0, stream>>>(rc, utt, R * B, qxF, 0,
                                           qxB, kvB, M * B, lng, lnb);
    // 2. summary (fp32 source) -> qxB rows [RT*B, Q*B)
    summary3_kernel<<<N * B, 256, 0, stream>>>(qxF, qxB);
    // 3. q projection (scaled)
    gemm(qxB, wq, bq, nullptr, f_q, nullptr, Q * B, MPAD, D, D, 0.125f, 0);
    // 4. fused k|v projection -> f_kv [4254][2048]
    gemm(kvB, wkv, bkv, nullptr, f_kv, nullptr, KV * B, MPAD, KVSTR, D, 1.0f, 0);
    // 5. sparse attention -> atB (bf16)
    attn4<<<N * B * H * 2, 256, 0, stream>>>(f_q, f_kv, lens, atB);
    // 6. output projection -> obuf (= f_q; q consumed)
    gemm(atB, wo, bo, nullptr, obuf, nullptr, Q * B, MPAD, D, D, 1.0f, 0);
    // 7. residual + mems clip
    resid_clip<<<(Q * B * D / 4 + 255) / 256, 256, 0, stream>>>(
        obuf, rc, utt, result, out + (size_t)(T + R) * B * D);
    // 8. FFN input LN -> flB
    ln2_kernel<<<RT * B, 256, 0, stream>>>(result, result, RT * B, nullptr, 0,
                                           flB, nullptr, 0, ffg, ffb);
    // 9. FFN up + relu -> fhB (bf16 epilogue)
    gemm(flB, w1, b1, nullptr, nullptr, fhB, RT * B, RT * B, FFN, D, 1.0f, 1);
    // 10. FFN down + residual -> res2
    gemm(fhB, w2, b2, result, res2, nullptr, RT * B, RT * B, D, FFN, 1.0f, 0);
    // 11. output LN with row remap -> out
    ln2_kernel<<<RT * B, 256, 0, stream>>>(res2, res2, RT * B, out, 1,
                                           nullptr, nullptr, 0, outg, outb);
}